// Round 5
// baseline (522.076 us; speedup 1.0000x reference)
//
#include <hip/hip_runtime.h>

#define C_DIM 256
#define HID_DIM 512
#define NHEAD 8
#define DHEAD 32
#define WWIN 512

typedef __attribute__((ext_vector_type(8))) short frag_ab;   // 8 bf16
typedef __attribute__((ext_vector_type(4))) short frag4;     // 4 bf16
typedef __attribute__((ext_vector_type(4))) float f32x4;

__device__ __forceinline__ float bf2f(unsigned int u16) {
    return __uint_as_float(u16 << 16);
}
__device__ __forceinline__ unsigned short f2bf(float f) {
    unsigned int x = __float_as_uint(f);
    return (unsigned short)((x + 0x7fffu + ((x >> 16) & 1u)) >> 16);
}
__device__ __forceinline__ void unpack8(uint4 u, float* d) {
    d[0] = bf2f(u.x & 0xffffu); d[1] = bf2f(u.x >> 16);
    d[2] = bf2f(u.y & 0xffffu); d[3] = bf2f(u.y >> 16);
    d[4] = bf2f(u.z & 0xffffu); d[5] = bf2f(u.z >> 16);
    d[6] = bf2f(u.w & 0xffffu); d[7] = bf2f(u.w >> 16);
}
// pack two f32 into two rounded bf16 in one v_perm
__device__ __forceinline__ unsigned int pk2(float lo, float hi) {
    return __builtin_amdgcn_perm(__float_as_uint(hi), __float_as_uint(lo), 0x07060302u);
}
// async 16B global->LDS (dest = uniform base + lane*16)
__device__ __forceinline__ void async_cp16(const void* g, void* l) {
    __builtin_amdgcn_global_load_lds(
        (const __attribute__((address_space(1))) unsigned int*)g,
        (__attribute__((address_space(3))) unsigned int*)l, 16, 0, 0);
}

// ---- per-row LayerNorm stats: one wave per row of 256 floats ----
__global__ __launch_bounds__(256) void rowstats_k(const float* __restrict__ X,
        float* __restrict__ mu, float* __restrict__ rs) {
    int lane = threadIdx.x & 63;
    int row = blockIdx.x * 4 + (threadIdx.x >> 6);
    float4 v = ((const float4*)(X + (size_t)row * C_DIM))[lane];
    float s = v.x + v.y + v.z + v.w;
    float q = v.x * v.x + v.y * v.y + v.z * v.z + v.w * v.w;
    #pragma unroll
    for (int o = 32; o; o >>= 1) { s += __shfl_xor(s, o); q += __shfl_xor(q, o); }
    if (lane == 0) {
        float m = s * (1.0f / C_DIM);
        float var = q * (1.0f / C_DIM) - m * m;
        mu[row] = m; rs[row] = rsqrtf(var + 1e-5f);
    }
}

// ---- window valid-lengths + inverse (token -> (window,offset)) map ----
__global__ __launch_bounds__(512) void wininv_k(const int* __restrict__ widx,
        int* __restrict__ wlen, int* __restrict__ cnt, int* __restrict__ inv) {
    int m = blockIdx.x, j = threadIdx.x;
    int id = widx[m * WWIN + j];
    int valid = (j == 0) || (id != widx[m * WWIN + j - 1]);
    __shared__ int part[8];
    int v = valid;
    #pragma unroll
    for (int o = 32; o; o >>= 1) v += __shfl_xor(v, o);
    if ((j & 63) == 0) part[j >> 6] = v;
    __syncthreads();
    if (j == 0) {
        int s = 0;
        #pragma unroll
        for (int i = 0; i < 8; i++) s += part[i];
        wlen[m] = s;
    }
    if (valid) {
        int slot = atomicAdd(&cnt[id], 1);
        if (slot < 2) inv[id * 2 + slot] = m * WWIN + j;
    }
}

// ---- convert the four weight matrices fp32 -> bf16 (one dispatch) ----
__global__ __launch_bounds__(256) void cvtw_k(
        const float* __restrict__ a, const float* __restrict__ b,
        const float* __restrict__ c, const float* __restrict__ d,
        unsigned short* __restrict__ oa, unsigned short* __restrict__ ob,
        unsigned short* __restrict__ oc, unsigned short* __restrict__ od) {
    int bi = blockIdx.x;
    const float* src; unsigned short* dst; int base;
    if (bi < 192)      { src = a; dst = oa; base = bi; }        // w_qkv 768x256
    else if (bi < 256) { src = b; dst = ob; base = bi - 192; }  // w_proj 256x256
    else if (bi < 384) { src = c; dst = oc; base = bi - 256; }  // w1 512x256
    else               { src = d; dst = od; base = bi - 384; }  // w2 256x512
    int i = base * 1024 + threadIdx.x * 4;
    float4 v = *(const float4*)(src + i);
    ushort4 o;
    o.x = f2bf(v.x); o.y = f2bf(v.y); o.z = f2bf(v.z); o.w = f2bf(v.w);
    *(ushort4*)(dst + i) = o;
}

// ---- MFMA GEMM: out[M,CN] = act_in(A) @ Bw[CN,K]^T (+post-ops) ----
// AMODE: 0 = bf16 A [M,K] via global_load_lds
//        4 = bf16 A head-split [K/32][M,32] via global_load_lds (AM = A rows)
//        1 = fp32 A, fused LayerNorm
//        3 = fp32 A, fused BN+ReLU
// OMODE: 0 = bf16; 1 = bf16 + bias; 2 = f32 + bias;
//        3 = f32 + bias + column-stat atomics; 4 = f32 + bias + resid;
//        5 = bf16 scatter to head-planes [(s*8+h)][token][32], CN = token count
template<int K, int AMODE, int OMODE>
__global__ __launch_bounds__(256, 2) void mgemm_k(
        const void* __restrict__ Av, const unsigned short* __restrict__ Bw,
        const float* __restrict__ bias, void* __restrict__ Outv,
        const float* __restrict__ rowmu, const float* __restrict__ rowrs,
        const float* __restrict__ colw, const float* __restrict__ colb,
        const float* __restrict__ resid, float* __restrict__ hsum,
        float* __restrict__ hsq, int CN, int AM) {
    __shared__ unsigned short As[4096];   // 128 rows x 4 slots x 8 bf16
    __shared__ unsigned short Bs[4096];
    const int t = threadIdx.x;
    const int w = t >> 6, lane = t & 63;
    const int Q = lane >> 4, n = lane & 15;
    const int r0 = blockIdx.y * 128, c0 = blockIdx.x * 128;
    const int qr0 = (w & 1) * 64, qc0 = (w >> 1) * 64;
    const f32x4 z4 = {0.f, 0.f, 0.f, 0.f};
    f32x4 acc[4][4];
    #pragma unroll
    for (int i = 0; i < 4; i++)
        #pragma unroll
        for (int j = 0; j < 4; j++) acc[i][j] = z4;

    for (int k0 = 0; k0 < K; k0 += 32) {
        if (k0) __syncthreads();
        // ---- stage B (async, swizzled dest order) ----
        #pragma unroll
        for (int i = 0; i < 2; i++) {
            int sbase = w * 128 + i * 64;
            int l = sbase + lane;
            int col = l >> 2;
            int sub = ((l & 3) - (col >> 1)) & 3;
            async_cp16(Bw + (size_t)(c0 + col) * K + k0 + sub * 8, &Bs[sbase * 8]);
        }
        // ---- stage A ----
        if constexpr (AMODE == 0 || AMODE == 4) {
            #pragma unroll
            for (int i = 0; i < 2; i++) {
                int sbase = w * 128 + i * 64;
                int l = sbase + lane;
                int row = l >> 2;
                int sub = ((l & 3) - (row >> 1)) & 3;
                const unsigned short* src;
                if constexpr (AMODE == 0)
                    src = (const unsigned short*)Av + (size_t)(r0 + row) * K + k0 + sub * 8;
                else
                    src = (const unsigned short*)Av + (size_t)k0 * AM + (size_t)(r0 + row) * 32 + sub * 8;
                async_cp16(src, &As[sbase * 8]);
            }
        } else {
            #pragma unroll
            for (int ii = 0; ii < 2; ii++) {
                int s = t + ii * 256;
                int row = s >> 2;
                int sub = ((s & 3) - (row >> 1)) & 3;
                const float* src = (const float*)Av + (size_t)(r0 + row) * K + k0 + sub * 8;
                float4 v0 = ((const float4*)src)[0];
                float4 v1 = ((const float4*)src)[1];
                float f[8] = {v0.x, v0.y, v0.z, v0.w, v1.x, v1.y, v1.z, v1.w};
                float4 cw0 = *(const float4*)(colw + k0 + sub * 8);
                float4 cw1 = *(const float4*)(colw + k0 + sub * 8 + 4);
                float4 cb0 = *(const float4*)(colb + k0 + sub * 8);
                float4 cb1 = *(const float4*)(colb + k0 + sub * 8 + 4);
                float cw[8] = {cw0.x, cw0.y, cw0.z, cw0.w, cw1.x, cw1.y, cw1.z, cw1.w};
                float cb[8] = {cb0.x, cb0.y, cb0.z, cb0.w, cb1.x, cb1.y, cb1.z, cb1.w};
                if constexpr (AMODE == 1) {
                    float rm = rowmu[r0 + row], rv = rowrs[r0 + row];
                    #pragma unroll
                    for (int j = 0; j < 8; j++) f[j] = (f[j] - rm) * rv * cw[j] + cb[j];
                } else {
                    #pragma unroll
                    for (int j = 0; j < 8; j++) f[j] = fmaxf(f[j] * cw[j] + cb[j], 0.f);
                }
                uint4 pkd;
                pkd.x = pk2(f[0], f[1]); pkd.y = pk2(f[2], f[3]);
                pkd.z = pk2(f[4], f[5]); pkd.w = pk2(f[6], f[7]);
                *(uint4*)&As[s * 8] = pkd;
            }
        }
        asm volatile("s_waitcnt vmcnt(0)" ::: "memory");
        __syncthreads();
        // ---- compute ----
        const int asub = (Q + (n >> 1)) & 3;
        frag_ab af[4], bfr[4];
        #pragma unroll
        for (int i = 0; i < 4; i++) {
            af[i]  = *(const frag_ab*)&As[((qr0 + i * 16 + n) * 4 + asub) * 8];
            bfr[i] = *(const frag_ab*)&Bs[((qc0 + i * 16 + n) * 4 + asub) * 8];
        }
        #pragma unroll
        for (int rt = 0; rt < 4; rt++)
            #pragma unroll
            for (int ct = 0; ct < 4; ct++)
                acc[rt][ct] = __builtin_amdgcn_mfma_f32_16x16x32_bf16(
                    af[rt], bfr[ct], acc[rt][ct], 0, 0, 0);
    }

    // ---- epilogue ----
    float sc[4] = {0.f, 0.f, 0.f, 0.f}, qc[4] = {0.f, 0.f, 0.f, 0.f};
    #pragma unroll
    for (int rt = 0; rt < 4; rt++) {
        #pragma unroll
        for (int ct = 0; ct < 4; ct++) {
            int mrow = r0 + qr0 + rt * 16 + Q * 4;
            int ccol = c0 + qc0 + ct * 16 + n;
            f32x4 a = acc[rt][ct];
            if constexpr (OMODE == 0) {
                unsigned short* dst = (unsigned short*)Outv + (size_t)mrow * CN + ccol;
                #pragma unroll
                for (int i = 0; i < 4; i++) dst[(size_t)i * CN] = f2bf(a[i]);
            } else if constexpr (OMODE == 1) {
                float bb = bias[ccol];
                unsigned short* dst = (unsigned short*)Outv + (size_t)mrow * CN + ccol;
                #pragma unroll
                for (int i = 0; i < 4; i++) dst[(size_t)i * CN] = f2bf(a[i] + bb);
            } else if constexpr (OMODE == 2) {
                float bb = bias[ccol];
                float* dst = (float*)Outv + (size_t)mrow * CN + ccol;
                #pragma unroll
                for (int i = 0; i < 4; i++) dst[(size_t)i * CN] = a[i] + bb;
            } else if constexpr (OMODE == 3) {
                float bb = bias[ccol];
                float* dst = (float*)Outv + (size_t)mrow * CN + ccol;
                #pragma unroll
                for (int i = 0; i < 4; i++) {
                    float v = a[i] + bb;
                    dst[(size_t)i * CN] = v;
                    sc[ct] += v; qc[ct] += v * v;
                }
            } else if constexpr (OMODE == 4) {
                float bb = bias[ccol];
                float* dst = (float*)Outv + (size_t)mrow * CN + ccol;
                const float* rr = resid + (size_t)mrow * CN + ccol;
                #pragma unroll
                for (int i = 0; i < 4; i++) dst[(size_t)i * CN] = a[i] + bb + rr[(size_t)i * CN];
            } else {
                // scatter to head planes: ccol = s*256 + h*32 + d
                int plane = ((ccol >> 8) << 3) | ((ccol >> 5) & 7);
                int d = ccol & 31;
                unsigned short* dst = (unsigned short*)Outv +
                    ((size_t)plane * CN + mrow) * 32 + d;
                #pragma unroll
                for (int i = 0; i < 4; i++) dst[i * 32] = f2bf(a[i]);
            }
        }
    }
    if constexpr (OMODE == 3) {
        #pragma unroll
        for (int ct = 0; ct < 4; ct++) {
            float s = sc[ct], q2 = qc[ct];
            s += __shfl_xor(s, 16); s += __shfl_xor(s, 32);
            q2 += __shfl_xor(q2, 16); q2 += __shfl_xor(q2, 32);
            if (Q == 0) {
                int ccol = c0 + qc0 + ct * 16 + n;
                atomicAdd(&hsum[ccol], s);
                atomicAdd(&hsq[ccol], q2);
            }
        }
    }
}

// ---- MFMA windowed attention, head-separated qkv planes ----
// qkv planes: Q = qkv[h][N][32], K = qkv[8+h][N][32], V = qkv[16+h][N][32].
// Window tokens are contiguous -> all global accesses dense/coalesced.
// Register-resident P (S^T C-layout == 16x16x16 B-operand layout).
#define KSTR 40    // K row stride in shorts (32 + 8 pad)
#define VSTR 136   // V^T row stride in shorts (128 + 8 pad)
__global__ __launch_bounds__(256, 4) void attn_mfma_k(
        const unsigned short* __restrict__ qkv, const int* __restrict__ widx,
        const int* __restrict__ wlen, unsigned short* __restrict__ aout,
        int N, int MW) {
    __shared__ unsigned short Kl[128 * KSTR];
    __shared__ unsigned short Vt[32 * VSTR];
    const int m = blockIdx.x >> 3, h = blockIdx.x & 7;
    const int t = threadIdx.x;
    const int w = t >> 6;
    const int lane = t & 63;
    const int Q = lane >> 4, n = lane & 15;
    const int len = wlen[m];
    const int* wrow = widx + m * WWIN;
    const unsigned short* Qp = qkv + (size_t)h * N * 32;
    const unsigned short* Kp = qkv + (size_t)(8 + h) * N * 32;
    const unsigned short* Vp = qkv + (size_t)(16 + h) * N * 32;
    const f32x4 z4 = {0.f, 0.f, 0.f, 0.f};

    // Q fragments (8 q-tiles), pre-scaled by 1/sqrt(DH) * log2(e)
    const float qs = 0.17677669529663687f * 1.4426950408889634f;
    frag_ab qf[8];
    #pragma unroll
    for (int qt = 0; qt < 8; qt++) {
        int q = w * 128 + qt * 16 + n;
        int tok = wrow[q];
        uint4 u = *(const uint4*)(Qp + (size_t)tok * 32 + Q * 8);
        float f[8]; unpack8(u, f);
        uint4 r;
        r.x = pk2(f[0] * qs, f[1] * qs); r.y = pk2(f[2] * qs, f[3] * qs);
        r.z = pk2(f[4] * qs, f[5] * qs); r.w = pk2(f[6] * qs, f[7] * qs);
        qf[qt] = __builtin_bit_cast(frag_ab, r);
    }

    f32x4 Ot[2][8];
    #pragma unroll
    for (int dt = 0; dt < 2; dt++)
        #pragma unroll
        for (int qt = 0; qt < 8; qt++) Ot[dt][qt] = z4;
    float rsum[8] = {0.f, 0.f, 0.f, 0.f, 0.f, 0.f, 0.f, 0.f};

    const int nchunk = (len + 127) >> 7;
    for (int c = 0; c < nchunk; c++) {
        const int kb = c << 7;
        __syncthreads();
        if (t < 128) {                       // stage V^T (transposed scatter)
            int r = t;
            int tok = wrow[kb + r];
            const uint4* src = (const uint4*)(Vp + (size_t)tok * 32);
            #pragma unroll
            for (int i = 0; i < 4; i++) {
                uint4 u = src[i];
                unsigned short* vp = &Vt[(i * 8) * VSTR + r];
                vp[0 * VSTR] = (unsigned short)(u.x & 0xffffu);
                vp[1 * VSTR] = (unsigned short)(u.x >> 16);
                vp[2 * VSTR] = (unsigned short)(u.y & 0xffffu);
                vp[3 * VSTR] = (unsigned short)(u.y >> 16);
                vp[4 * VSTR] = (unsigned short)(u.z & 0xffffu);
                vp[5 * VSTR] = (unsigned short)(u.z >> 16);
                vp[6 * VSTR] = (unsigned short)(u.w & 0xffffu);
                vp[7 * VSTR] = (unsigned short)(u.w >> 16);
            }
        } else {                             // stage K rows (rotated, padded)
            int r = t - 128;
            int tok = wrow[kb + r];
            const uint4* src = (const uint4*)(Kp + (size_t)tok * 32);
            #pragma unroll
            for (int i = 0; i < 4; i++) {
                int c4 = (r + i) & 3;
                *(uint4*)&Kl[r * KSTR + c4 * 8] = src[c4];
            }
        }
        __syncthreads();
        int rem = len - kb; if (rem > 128) rem = 128;
        const int nsub = (rem + 31) >> 5;
        for (int s = 0; s < nsub; s++) {
            const int lim = rem - s * 32;
            frag_ab kf0 = *(const frag_ab*)&Kl[(s * 32 + n) * KSTR + Q * 8];
            frag_ab kf1 = *(const frag_ab*)&Kl[(s * 32 + 16 + n) * KSTR + Q * 8];
            frag4 va00 = *(const frag4*)&Vt[n * VSTR + s * 32 + 4 * Q];
            frag4 va01 = *(const frag4*)&Vt[n * VSTR + s * 32 + 16 + 4 * Q];
            frag4 va10 = *(const frag4*)&Vt[(16 + n) * VSTR + s * 32 + 4 * Q];
            frag4 va11 = *(const frag4*)&Vt[(16 + n) * VSTR + s * 32 + 16 + 4 * Q];
            #pragma unroll
            for (int qt = 0; qt < 8; qt++) {
                f32x4 s0 = __builtin_amdgcn_mfma_f32_16x16x32_bf16(kf0, qf[qt], z4, 0, 0, 0);
                f32x4 s1 = __builtin_amdgcn_mfma_f32_16x16x32_bf16(kf1, qf[qt], z4, 0, 0, 0);
                float e[8];
                #pragma unroll
                for (int i = 0; i < 4; i++) {
                    e[i]     = __builtin_amdgcn_exp2f(s0[i]);
                    e[4 + i] = __builtin_amdgcn_exp2f(s1[i]);
                }
                if (lim < 32) {
                    #pragma unroll
                    for (int i = 0; i < 4; i++) {
                        if (4 * Q + i >= lim)      e[i] = 0.f;
                        if (16 + 4 * Q + i >= lim) e[4 + i] = 0.f;
                    }
                }
                float rsq = rsum[qt];
                #pragma unroll
                for (int i = 0; i < 8; i++) rsq += e[i];
                rsum[qt] = rsq;
                uint2 u0, u1;
                u0.x = pk2(e[0], e[1]); u0.y = pk2(e[2], e[3]);
                u1.x = pk2(e[4], e[5]); u1.y = pk2(e[6], e[7]);
                frag4 p0 = __builtin_bit_cast(frag4, u0);
                frag4 p1 = __builtin_bit_cast(frag4, u1);
                Ot[0][qt] = __builtin_amdgcn_mfma_f32_16x16x16bf16_1k(va00, p0, Ot[0][qt], 0, 0, 0);
                Ot[0][qt] = __builtin_amdgcn_mfma_f32_16x16x16bf16_1k(va01, p1, Ot[0][qt], 0, 0, 0);
                Ot[1][qt] = __builtin_amdgcn_mfma_f32_16x16x16bf16_1k(va10, p0, Ot[1][qt], 0, 0, 0);
                Ot[1][qt] = __builtin_amdgcn_mfma_f32_16x16x16bf16_1k(va11, p1, Ot[1][qt], 0, 0, 0);
            }
        }
    }

    #pragma unroll
    for (int qt = 0; qt < 8; qt++) {
        float r = rsum[qt];
        r += __shfl_xor(r, 16);
        r += __shfl_xor(r, 32);
        float inv = 1.f / r;
        int q = w * 128 + qt * 16 + n;
        unsigned short* dst = aout + ((size_t)h * MW + (size_t)(m * WWIN + q)) * 32;
        #pragma unroll
        for (int dt = 0; dt < 2; dt++) {
            f32x4 o = Ot[dt][qt];
            uint2 pk;
            pk.x = pk2(o[0] * inv, o[1] * inv);
            pk.y = pk2(o[2] * inv, o[3] * inv);
            *(uint2*)(dst + dt * 16 + 4 * Q) = pk;
        }
    }
}

// ---- combine: x1 = x + gathered(out_proj bf16)/count, plus LN2 row stats ----
__global__ __launch_bounds__(256) void combine_k(
        const float* __restrict__ x, const unsigned short* __restrict__ proj,
        const int* __restrict__ cnt, const int* __restrict__ inv,
        float* __restrict__ x1, float* __restrict__ mu, float* __restrict__ rs) {
    int lane = threadIdx.x & 63;
    int row = blockIdx.x * 4 + (threadIdx.x >> 6);
    int c = cnt[row];
    if (c > 2) c = 2;
    float4 acc = make_float4(0.f, 0.f, 0.f, 0.f);
    for (int s = 0; s < c; s++) {
        int src = inv[row * 2 + s];
        uint2 p = ((const uint2*)(proj + (size_t)src * C_DIM))[lane];
        acc.x += bf2f(p.x & 0xffffu); acc.y += bf2f(p.x >> 16);
        acc.z += bf2f(p.y & 0xffffu); acc.w += bf2f(p.y >> 16);
    }
    float ic = 1.f / (float)(c > 0 ? c : 1);
    float4 xv = ((const float4*)(x + (size_t)row * C_DIM))[lane];
    float4 r4;
    r4.x = xv.x + acc.x * ic; r4.y = xv.y + acc.y * ic;
    r4.z = xv.z + acc.z * ic; r4.w = xv.w + acc.w * ic;
    ((float4*)(x1 + (size_t)row * C_DIM))[lane] = r4;
    float s = r4.x + r4.y + r4.z + r4.w;
    float q = r4.x * r4.x + r4.y * r4.y + r4.z * r4.z + r4.w * r4.w;
    #pragma unroll
    for (int o = 32; o; o >>= 1) { s += __shfl_xor(s, o); q += __shfl_xor(q, o); }
    if (lane == 0) {
        float mm = s * (1.f / C_DIM);
        float var = q * (1.f / C_DIM) - mm * mm;
        mu[row] = mm; rs[row] = rsqrtf(var + 1e-5f);
    }
}

__global__ void bnfin_k(const float* __restrict__ hsum, const float* __restrict__ hsq,
        const float* __restrict__ bnw, const float* __restrict__ bnb,
        float* __restrict__ premul, float* __restrict__ preadd, float inv_n) {
    int c = threadIdx.x;
    float m = hsum[c] * inv_n;
    float var = hsq[c] * inv_n - m * m;
    float rstd = rsqrtf(var + 1e-5f);
    float pm = rstd * bnw[c];
    premul[c] = pm;
    preadd[c] = bnb[c] - m * pm;
}

extern "C" void kernel_launch(void* const* d_in, const int* in_sizes, int n_in,
                              void* d_out, int out_size, void* d_ws, size_t ws_size,
                              hipStream_t stream) {
    const float* x    = (const float*)d_in[0];
    const int* widx   = (const int*)d_in[1];
    const float* ln1w = (const float*)d_in[3];
    const float* ln1b = (const float*)d_in[4];
    const float* wqkv = (const float*)d_in[5];
    const float* wproj = (const float*)d_in[6];
    const float* bproj = (const float*)d_in[7];
    const float* ln2w = (const float*)d_in[8];
    const float* ln2b = (const float*)d_in[9];
    const float* w1   = (const float*)d_in[10];
    const float* b1   = (const float*)d_in[11];
    const float* bnw  = (const float*)d_in[12];
    const float* bnb  = (const float*)d_in[13];
    const float* w2   = (const float*)d_in[14];
    const float* b2   = (const float*)d_in[15];
    float* out = (float*)d_out;

    const int N  = in_sizes[0] / C_DIM;   // 25600
    const int MW = in_sizes[1];           // M * 512
    const int M  = MW / WWIN;             // 100

    char* w = (char*)d_ws;
    size_t off = 0;
    auto alloc = [&](size_t bytes) -> void* {
        void* p = w + off;
        off += (bytes + 255) & ~(size_t)255;
        return p;
    };
    // Region A: qkv bf16 planes [24][N][32] -> out_proj bf16 [MW,256] -> h f32 [N,512]
    size_t szA = (size_t)MW * C_DIM * 4;
    void* regA = alloc(szA);
    unsigned short* qkv = (unsigned short*)regA;
    unsigned short* out_proj = (unsigned short*)regA;
    float* hbuf = (float*)regA;
    // Region B: attn_out bf16 planes [8][MW][32] -> x1 f32 [N,256]
    size_t szB = (size_t)MW * C_DIM * 2;
    void* regB = alloc(szB);
    unsigned short* attn_out = (unsigned short*)regB;
    float* x1 = (float*)regB;

    unsigned short* wqkv_bf = (unsigned short*)alloc(768 * 256 * 2);
    unsigned short* wproj_bf = (unsigned short*)alloc(256 * 256 * 2);
    unsigned short* w1_bf = (unsigned short*)alloc(512 * 256 * 2);
    unsigned short* w2_bf = (unsigned short*)alloc(256 * 512 * 2);

    float* mu0 = (float*)alloc((size_t)N * 4);
    float* rs0 = (float*)alloc((size_t)N * 4);
    float* mu1 = (float*)alloc((size_t)N * 4);
    float* rs1 = (float*)alloc((size_t)N * 4);
    int* cnt   = (int*)alloc((size_t)N * 4);
    int* inv   = (int*)alloc((size_t)N * 8);
    int* wlen  = (int*)alloc((size_t)M * 4);
    float* hsum = (float*)alloc(HID_DIM * 4);
    float* hsq  = (float*)alloc(HID_DIM * 4);
    float* premul = (float*)alloc(HID_DIM * 4);
    float* preadd = (float*)alloc(HID_DIM * 4);

    hipMemsetAsync(cnt, 0, (size_t)N * 4, stream);
    hipMemsetAsync(hsum, 0, HID_DIM * 4, stream);
    hipMemsetAsync(hsq, 0, HID_DIM * 4, stream);

    cvtw_k<<<512, 256, 0, stream>>>(wqkv, wproj, w1, w2, wqkv_bf, wproj_bf, w1_bf, w2_bf);
    rowstats_k<<<N / 4, 256, 0, stream>>>(x, mu0, rs0);
    wininv_k<<<M, 512, 0, stream>>>(widx, wlen, cnt, inv);
    // QKV = LN1(x) @ w_qkv^T, scattered to head planes [24][N][32]
    mgemm_k<256, 1, 5><<<dim3(768 / 128, N / 128), 256, 0, stream>>>(
        x, wqkv_bf, nullptr, qkv, mu0, rs0, ln1w, ln1b, nullptr, nullptr, nullptr, N, 0);
    attn_mfma_k<<<M * NHEAD, 256, 0, stream>>>(qkv, widx, wlen, attn_out, N, MW);
    // out_proj = attn @ w_proj^T + b_proj (A = head-split planes, AM = MW)
    mgemm_k<256, 4, 1><<<dim3(256 / 128, MW / 128), 256, 0, stream>>>(
        attn_out, wproj_bf, bproj, out_proj, nullptr, nullptr, nullptr, nullptr,
        nullptr, nullptr, nullptr, 256, MW);
    combine_k<<<N / 4, 256, 0, stream>>>(x, out_proj, cnt, inv, x1, mu1, rs1);
    // h = LN2(x1) @ w1^T + b1, with fused BN column stats
    mgemm_k<256, 1, 3><<<dim3(512 / 128, N / 128), 256, 0, stream>>>(
        x1, w1_bf, b1, hbuf, mu1, rs1, ln2w, ln2b, nullptr, hsum, hsq, 512, 0);
    bnfin_k<<<1, HID_DIM, 0, stream>>>(hsum, hsq, bnw, bnb, premul, preadd, 1.0f / (float)N);
    // out = x1 + relu(BN(h)) @ w2^T + b2
    mgemm_k<512, 3, 4><<<dim3(256 / 128, N / 128), 256, 0, stream>>>(
        hbuf, w2_bf, b2, out, nullptr, nullptr, premul, preadd, x1, nullptr, nullptr, 256, 0);
}

// Round 6
// 347.266 us; speedup vs baseline: 1.5034x; 1.5034x over previous
//
#include <hip/hip_runtime.h>

#define C_DIM 256
#define HID_DIM 512
#define NHEAD 8
#define DHEAD 32
#define WWIN 512

typedef __attribute__((ext_vector_type(8))) short frag_ab;   // 8 bf16
typedef __attribute__((ext_vector_type(4))) short frag4;     // 4 bf16
typedef __attribute__((ext_vector_type(4))) float f32x4;

__device__ __forceinline__ float bf2f(unsigned int u16) {
    return __uint_as_float(u16 << 16);
}
__device__ __forceinline__ unsigned short f2bf(float f) {
    unsigned int x = __float_as_uint(f);
    return (unsigned short)((x + 0x7fffu + ((x >> 16) & 1u)) >> 16);
}
__device__ __forceinline__ void unpack8(uint4 u, float* d) {
    d[0] = bf2f(u.x & 0xffffu); d[1] = bf2f(u.x >> 16);
    d[2] = bf2f(u.y & 0xffffu); d[3] = bf2f(u.y >> 16);
    d[4] = bf2f(u.z & 0xffffu); d[5] = bf2f(u.z >> 16);
    d[6] = bf2f(u.w & 0xffffu); d[7] = bf2f(u.w >> 16);
}
// pack two f32 into two rounded bf16 in one v_perm
__device__ __forceinline__ unsigned int pk2(float lo, float hi) {
    return __builtin_amdgcn_perm(__float_as_uint(hi), __float_as_uint(lo), 0x07060302u);
}
// async 16B global->LDS (dest = uniform base + lane*16)
__device__ __forceinline__ void async_cp16(const void* g, void* l) {
    __builtin_amdgcn_global_load_lds(
        (const __attribute__((address_space(1))) unsigned int*)g,
        (__attribute__((address_space(3))) unsigned int*)l, 16, 0, 0);
}

// ---- per-row LayerNorm stats: one wave per row of 256 floats ----
__global__ __launch_bounds__(256) void rowstats_k(const float* __restrict__ X,
        float* __restrict__ mu, float* __restrict__ rs) {
    int lane = threadIdx.x & 63;
    int row = blockIdx.x * 4 + (threadIdx.x >> 6);
    float4 v = ((const float4*)(X + (size_t)row * C_DIM))[lane];
    float s = v.x + v.y + v.z + v.w;
    float q = v.x * v.x + v.y * v.y + v.z * v.z + v.w * v.w;
    #pragma unroll
    for (int o = 32; o; o >>= 1) { s += __shfl_xor(s, o); q += __shfl_xor(q, o); }
    if (lane == 0) {
        float m = s * (1.0f / C_DIM);
        float var = q * (1.0f / C_DIM) - m * m;
        mu[row] = m; rs[row] = rsqrtf(var + 1e-5f);
    }
}

// ---- window valid-lengths + inverse (token -> (window,offset)) map ----
__global__ __launch_bounds__(512) void wininv_k(const int* __restrict__ widx,
        int* __restrict__ wlen, int* __restrict__ cnt, int* __restrict__ inv) {
    int m = blockIdx.x, j = threadIdx.x;
    int id = widx[m * WWIN + j];
    int valid = (j == 0) || (id != widx[m * WWIN + j - 1]);
    __shared__ int part[8];
    int v = valid;
    #pragma unroll
    for (int o = 32; o; o >>= 1) v += __shfl_xor(v, o);
    if ((j & 63) == 0) part[j >> 6] = v;
    __syncthreads();
    if (j == 0) {
        int s = 0;
        #pragma unroll
        for (int i = 0; i < 8; i++) s += part[i];
        wlen[m] = s;
    }
    if (valid) {
        int slot = atomicAdd(&cnt[id], 1);
        if (slot < 2) inv[id * 2 + slot] = m * WWIN + j;
    }
}

// ---- convert the four weight matrices fp32 -> bf16 (one dispatch) ----
__global__ __launch_bounds__(256) void cvtw_k(
        const float* __restrict__ a, const float* __restrict__ b,
        const float* __restrict__ c, const float* __restrict__ d,
        unsigned short* __restrict__ oa, unsigned short* __restrict__ ob,
        unsigned short* __restrict__ oc, unsigned short* __restrict__ od) {
    int bi = blockIdx.x;
    const float* src; unsigned short* dst; int base;
    if (bi < 192)      { src = a; dst = oa; base = bi; }        // w_qkv 768x256
    else if (bi < 256) { src = b; dst = ob; base = bi - 192; }  // w_proj 256x256
    else if (bi < 384) { src = c; dst = oc; base = bi - 256; }  // w1 512x256
    else               { src = d; dst = od; base = bi - 384; }  // w2 256x512
    int i = base * 1024 + threadIdx.x * 4;
    float4 v = *(const float4*)(src + i);
    ushort4 o;
    o.x = f2bf(v.x); o.y = f2bf(v.y); o.z = f2bf(v.z); o.w = f2bf(v.w);
    *(ushort4*)(dst + i) = o;
}

// ---- MFMA GEMM: out[M,CN] = act_in(A) @ Bw[CN,K]^T (+post-ops) ----
// AMODE: 0 = bf16 A [M,K] via global_load_lds
//        4 = bf16 A head-split [K/32][M,32] via global_load_lds (AM = A rows)
//        1 = fp32 A, fused LayerNorm
//        3 = fp32 A, fused BN+ReLU
// OMODE: 0 = bf16; 1 = bf16 + bias; 2 = f32 + bias;
//        3 = f32 + bias + column-stat atomics; 4 = f32 + bias + resid;
//        5 = bf16 scatter to head-planes [(s*8+h)][token][32], CN = token count
template<int K, int AMODE, int OMODE>
__global__ __launch_bounds__(256, 2) void mgemm_k(
        const void* __restrict__ Av, const unsigned short* __restrict__ Bw,
        const float* __restrict__ bias, void* __restrict__ Outv,
        const float* __restrict__ rowmu, const float* __restrict__ rowrs,
        const float* __restrict__ colw, const float* __restrict__ colb,
        const float* __restrict__ resid, float* __restrict__ hsum,
        float* __restrict__ hsq, int CN, int AM) {
    __shared__ unsigned short As[4096];   // 128 rows x 4 slots x 8 bf16
    __shared__ unsigned short Bs[4096];
    const int t = threadIdx.x;
    const int w = t >> 6, lane = t & 63;
    const int Q = lane >> 4, n = lane & 15;
    const int r0 = blockIdx.y * 128, c0 = blockIdx.x * 128;
    const int qr0 = (w & 1) * 64, qc0 = (w >> 1) * 64;
    const f32x4 z4 = {0.f, 0.f, 0.f, 0.f};
    f32x4 acc[4][4];
    #pragma unroll
    for (int i = 0; i < 4; i++)
        #pragma unroll
        for (int j = 0; j < 4; j++) acc[i][j] = z4;

    for (int k0 = 0; k0 < K; k0 += 32) {
        if (k0) __syncthreads();
        // ---- stage B (async, swizzled dest order) ----
        #pragma unroll
        for (int i = 0; i < 2; i++) {
            int sbase = w * 128 + i * 64;
            int l = sbase + lane;
            int col = l >> 2;
            int sub = ((l & 3) - (col >> 1)) & 3;
            async_cp16(Bw + (size_t)(c0 + col) * K + k0 + sub * 8, &Bs[sbase * 8]);
        }
        // ---- stage A ----
        if constexpr (AMODE == 0 || AMODE == 4) {
            #pragma unroll
            for (int i = 0; i < 2; i++) {
                int sbase = w * 128 + i * 64;
                int l = sbase + lane;
                int row = l >> 2;
                int sub = ((l & 3) - (row >> 1)) & 3;
                const unsigned short* src;
                if constexpr (AMODE == 0)
                    src = (const unsigned short*)Av + (size_t)(r0 + row) * K + k0 + sub * 8;
                else
                    src = (const unsigned short*)Av + (size_t)k0 * AM + (size_t)(r0 + row) * 32 + sub * 8;
                async_cp16(src, &As[sbase * 8]);
            }
        } else {
            #pragma unroll
            for (int ii = 0; ii < 2; ii++) {
                int s = t + ii * 256;
                int row = s >> 2;
                int sub = ((s & 3) - (row >> 1)) & 3;
                const float* src = (const float*)Av + (size_t)(r0 + row) * K + k0 + sub * 8;
                float4 v0 = ((const float4*)src)[0];
                float4 v1 = ((const float4*)src)[1];
                float f[8] = {v0.x, v0.y, v0.z, v0.w, v1.x, v1.y, v1.z, v1.w};
                float4 cw0 = *(const float4*)(colw + k0 + sub * 8);
                float4 cw1 = *(const float4*)(colw + k0 + sub * 8 + 4);
                float4 cb0 = *(const float4*)(colb + k0 + sub * 8);
                float4 cb1 = *(const float4*)(colb + k0 + sub * 8 + 4);
                float cw[8] = {cw0.x, cw0.y, cw0.z, cw0.w, cw1.x, cw1.y, cw1.z, cw1.w};
                float cb[8] = {cb0.x, cb0.y, cb0.z, cb0.w, cb1.x, cb1.y, cb1.z, cb1.w};
                if constexpr (AMODE == 1) {
                    float rm = rowmu[r0 + row], rv = rowrs[r0 + row];
                    #pragma unroll
                    for (int j = 0; j < 8; j++) f[j] = (f[j] - rm) * rv * cw[j] + cb[j];
                } else {
                    #pragma unroll
                    for (int j = 0; j < 8; j++) f[j] = fmaxf(f[j] * cw[j] + cb[j], 0.f);
                }
                uint4 pkd;
                pkd.x = pk2(f[0], f[1]); pkd.y = pk2(f[2], f[3]);
                pkd.z = pk2(f[4], f[5]); pkd.w = pk2(f[6], f[7]);
                *(uint4*)&As[s * 8] = pkd;
            }
        }
        asm volatile("s_waitcnt vmcnt(0)" ::: "memory");
        __syncthreads();
        // ---- compute ----
        const int asub = (Q + (n >> 1)) & 3;
        frag_ab af[4], bfr[4];
        #pragma unroll
        for (int i = 0; i < 4; i++) {
            af[i]  = *(const frag_ab*)&As[((qr0 + i * 16 + n) * 4 + asub) * 8];
            bfr[i] = *(const frag_ab*)&Bs[((qc0 + i * 16 + n) * 4 + asub) * 8];
        }
        #pragma unroll
        for (int rt = 0; rt < 4; rt++)
            #pragma unroll
            for (int ct = 0; ct < 4; ct++)
                acc[rt][ct] = __builtin_amdgcn_mfma_f32_16x16x32_bf16(
                    af[rt], bfr[ct], acc[rt][ct], 0, 0, 0);
    }

    // ---- epilogue ----
    float sc[4] = {0.f, 0.f, 0.f, 0.f}, qc[4] = {0.f, 0.f, 0.f, 0.f};
    #pragma unroll
    for (int rt = 0; rt < 4; rt++) {
        #pragma unroll
        for (int ct = 0; ct < 4; ct++) {
            int mrow = r0 + qr0 + rt * 16 + Q * 4;
            int ccol = c0 + qc0 + ct * 16 + n;
            f32x4 a = acc[rt][ct];
            if constexpr (OMODE == 0) {
                unsigned short* dst = (unsigned short*)Outv + (size_t)mrow * CN + ccol;
                #pragma unroll
                for (int i = 0; i < 4; i++) dst[(size_t)i * CN] = f2bf(a[i]);
            } else if constexpr (OMODE == 1) {
                float bb = bias[ccol];
                unsigned short* dst = (unsigned short*)Outv + (size_t)mrow * CN + ccol;
                #pragma unroll
                for (int i = 0; i < 4; i++) dst[(size_t)i * CN] = f2bf(a[i] + bb);
            } else if constexpr (OMODE == 2) {
                float bb = bias[ccol];
                float* dst = (float*)Outv + (size_t)mrow * CN + ccol;
                #pragma unroll
                for (int i = 0; i < 4; i++) dst[(size_t)i * CN] = a[i] + bb;
            } else if constexpr (OMODE == 3) {
                float bb = bias[ccol];
                float* dst = (float*)Outv + (size_t)mrow * CN + ccol;
                #pragma unroll
                for (int i = 0; i < 4; i++) {
                    float v = a[i] + bb;
                    dst[(size_t)i * CN] = v;
                    sc[ct] += v; qc[ct] += v * v;
                }
            } else if constexpr (OMODE == 4) {
                float bb = bias[ccol];
                float* dst = (float*)Outv + (size_t)mrow * CN + ccol;
                const float* rr = resid + (size_t)mrow * CN + ccol;
                #pragma unroll
                for (int i = 0; i < 4; i++) dst[(size_t)i * CN] = a[i] + bb + rr[(size_t)i * CN];
            } else {
                // scatter to head planes: ccol = s*256 + h*32 + d
                int plane = ((ccol >> 8) << 3) | ((ccol >> 5) & 7);
                int d = ccol & 31;
                unsigned short* dst = (unsigned short*)Outv +
                    ((size_t)plane * CN + mrow) * 32 + d;
                #pragma unroll
                for (int i = 0; i < 4; i++) dst[i * 32] = f2bf(a[i]);
            }
        }
    }
    if constexpr (OMODE == 3) {
        #pragma unroll
        for (int ct = 0; ct < 4; ct++) {
            float s = sc[ct], q2 = qc[ct];
            s += __shfl_xor(s, 16); s += __shfl_xor(s, 32);
            q2 += __shfl_xor(q2, 16); q2 += __shfl_xor(q2, 32);
            if (Q == 0) {
                int ccol = c0 + qc0 + ct * 16 + n;
                atomicAdd(&hsum[ccol], s);
                atomicAdd(&hsq[ccol], q2);
            }
        }
    }
}

// ---- MFMA windowed attention, head-separated qkv planes ----
// qkv planes: Q = qkv[h][N][32], K = qkv[8+h][N][32], V = qkv[16+h][N][32].
// Window tokens are contiguous -> all global accesses dense/coalesced.
// Register-resident P (S^T C-layout == 16x16x16 B-operand layout).
// NOTE: __launch_bounds__(256,3) — NOT 4. (256,4) caps VGPR at 64 and the
// kernel needs ~84 (qf[8]+Ot[2][8]); the cap spilled qf/Ot to scratch and
// generated ~1 GB of spill traffic (R5 post-mortem: FETCH 481 MB/WRITE 570 MB).
#define KSTR 40    // K row stride in shorts (32 + 8 pad)
#define VSTR 136   // V^T row stride in shorts (128 + 8 pad)
__global__ __launch_bounds__(256, 3) void attn_mfma_k(
        const unsigned short* __restrict__ qkv, const int* __restrict__ widx,
        const int* __restrict__ wlen, unsigned short* __restrict__ aout,
        int N, int MW) {
    __shared__ unsigned short Kl[128 * KSTR];
    __shared__ unsigned short Vt[32 * VSTR];
    const int m = blockIdx.x >> 3, h = blockIdx.x & 7;
    const int t = threadIdx.x;
    const int w = t >> 6;
    const int lane = t & 63;
    const int Q = lane >> 4, n = lane & 15;
    const int len = wlen[m];
    const int* wrow = widx + m * WWIN;
    const unsigned short* Qp = qkv + (size_t)h * N * 32;
    const unsigned short* Kp = qkv + (size_t)(8 + h) * N * 32;
    const unsigned short* Vp = qkv + (size_t)(16 + h) * N * 32;
    const f32x4 z4 = {0.f, 0.f, 0.f, 0.f};

    // Q fragments (8 q-tiles), pre-scaled by 1/sqrt(DH) * log2(e)
    const float qs = 0.17677669529663687f * 1.4426950408889634f;
    frag_ab qf[8];
    #pragma unroll
    for (int qt = 0; qt < 8; qt++) {
        int q = w * 128 + qt * 16 + n;
        int tok = wrow[q];
        uint4 u = *(const uint4*)(Qp + (size_t)tok * 32 + Q * 8);
        float f[8]; unpack8(u, f);
        uint4 r;
        r.x = pk2(f[0] * qs, f[1] * qs); r.y = pk2(f[2] * qs, f[3] * qs);
        r.z = pk2(f[4] * qs, f[5] * qs); r.w = pk2(f[6] * qs, f[7] * qs);
        qf[qt] = __builtin_bit_cast(frag_ab, r);
    }

    f32x4 Ot[2][8];
    #pragma unroll
    for (int dt = 0; dt < 2; dt++)
        #pragma unroll
        for (int qt = 0; qt < 8; qt++) Ot[dt][qt] = z4;
    float rsum[8] = {0.f, 0.f, 0.f, 0.f, 0.f, 0.f, 0.f, 0.f};

    const int nchunk = (len + 127) >> 7;
    for (int c = 0; c < nchunk; c++) {
        const int kb = c << 7;
        __syncthreads();
        if (t < 128) {                       // stage V^T (transposed scatter)
            int r = t;
            int tok = wrow[kb + r];
            const uint4* src = (const uint4*)(Vp + (size_t)tok * 32);
            #pragma unroll
            for (int i = 0; i < 4; i++) {
                uint4 u = src[i];
                unsigned short* vp = &Vt[(i * 8) * VSTR + r];
                vp[0 * VSTR] = (unsigned short)(u.x & 0xffffu);
                vp[1 * VSTR] = (unsigned short)(u.x >> 16);
                vp[2 * VSTR] = (unsigned short)(u.y & 0xffffu);
                vp[3 * VSTR] = (unsigned short)(u.y >> 16);
                vp[4 * VSTR] = (unsigned short)(u.z & 0xffffu);
                vp[5 * VSTR] = (unsigned short)(u.z >> 16);
                vp[6 * VSTR] = (unsigned short)(u.w & 0xffffu);
                vp[7 * VSTR] = (unsigned short)(u.w >> 16);
            }
        } else {                             // stage K rows (rotated, padded)
            int r = t - 128;
            int tok = wrow[kb + r];
            const uint4* src = (const uint4*)(Kp + (size_t)tok * 32);
            #pragma unroll
            for (int i = 0; i < 4; i++) {
                int c4 = (r + i) & 3;
                *(uint4*)&Kl[r * KSTR + c4 * 8] = src[c4];
            }
        }
        __syncthreads();
        int rem = len - kb; if (rem > 128) rem = 128;
        const int nsub = (rem + 31) >> 5;
        for (int s = 0; s < nsub; s++) {
            const int lim = rem - s * 32;
            frag_ab kf0 = *(const frag_ab*)&Kl[(s * 32 + n) * KSTR + Q * 8];
            frag_ab kf1 = *(const frag_ab*)&Kl[(s * 32 + 16 + n) * KSTR + Q * 8];
            frag4 va00 = *(const frag4*)&Vt[n * VSTR + s * 32 + 4 * Q];
            frag4 va01 = *(const frag4*)&Vt[n * VSTR + s * 32 + 16 + 4 * Q];
            frag4 va10 = *(const frag4*)&Vt[(16 + n) * VSTR + s * 32 + 4 * Q];
            frag4 va11 = *(const frag4*)&Vt[(16 + n) * VSTR + s * 32 + 16 + 4 * Q];
            #pragma unroll
            for (int qt = 0; qt < 8; qt++) {
                f32x4 s0 = __builtin_amdgcn_mfma_f32_16x16x32_bf16(kf0, qf[qt], z4, 0, 0, 0);
                f32x4 s1 = __builtin_amdgcn_mfma_f32_16x16x32_bf16(kf1, qf[qt], z4, 0, 0, 0);
                float e[8];
                #pragma unroll
                for (int i = 0; i < 4; i++) {
                    e[i]     = __builtin_amdgcn_exp2f(s0[i]);
                    e[4 + i] = __builtin_amdgcn_exp2f(s1[i]);
                }
                if (lim < 32) {
                    #pragma unroll
                    for (int i = 0; i < 4; i++) {
                        if (4 * Q + i >= lim)      e[i] = 0.f;
                        if (16 + 4 * Q + i >= lim) e[4 + i] = 0.f;
                    }
                }
                float rsq = rsum[qt];
                #pragma unroll
                for (int i = 0; i < 8; i++) rsq += e[i];
                rsum[qt] = rsq;
                uint2 u0, u1;
                u0.x = pk2(e[0], e[1]); u0.y = pk2(e[2], e[3]);
                u1.x = pk2(e[4], e[5]); u1.y = pk2(e[6], e[7]);
                frag4 p0 = __builtin_bit_cast(frag4, u0);
                frag4 p1 = __builtin_bit_cast(frag4, u1);
                Ot[0][qt] = __builtin_amdgcn_mfma_f32_16x16x16bf16_1k(va00, p0, Ot[0][qt], 0, 0, 0);
                Ot[0][qt] = __builtin_amdgcn_mfma_f32_16x16x16bf16_1k(va01, p1, Ot[0][qt], 0, 0, 0);
                Ot[1][qt] = __builtin_amdgcn_mfma_f32_16x16x16bf16_1k(va10, p0, Ot[1][qt], 0, 0, 0);
                Ot[1][qt] = __builtin_amdgcn_mfma_f32_16x16x16bf16_1k(va11, p1, Ot[1][qt], 0, 0, 0);
            }
        }
    }

    #pragma unroll
    for (int qt = 0; qt < 8; qt++) {
        float r = rsum[qt];
        r += __shfl_xor(r, 16);
        r += __shfl_xor(r, 32);
        float inv = 1.f / r;
        int q = w * 128 + qt * 16 + n;
        unsigned short* dst = aout + ((size_t)h * MW + (size_t)(m * WWIN + q)) * 32;
        #pragma unroll
        for (int dt = 0; dt < 2; dt++) {
            f32x4 o = Ot[dt][qt];
            uint2 pk;
            pk.x = pk2(o[0] * inv, o[1] * inv);
            pk.y = pk2(o[2] * inv, o[3] * inv);
            *(uint2*)(dst + dt * 16 + 4 * Q) = pk;
        }
    }
}

// ---- combine: x1 = x + gathered(out_proj bf16)/count, plus LN2 row stats ----
__global__ __launch_bounds__(256) void combine_k(
        const float* __restrict__ x, const unsigned short* __restrict__ proj,
        const int* __restrict__ cnt, const int* __restrict__ inv,
        float* __restrict__ x1, float* __restrict__ mu, float* __restrict__ rs) {
    int lane = threadIdx.x & 63;
    int row = blockIdx.x * 4 + (threadIdx.x >> 6);
    int c = cnt[row];
    if (c > 2) c = 2;
    float4 acc = make_float4(0.f, 0.f, 0.f, 0.f);
    for (int s = 0; s < c; s++) {
        int src = inv[row * 2 + s];
        uint2 p = ((const uint2*)(proj + (size_t)src * C_DIM))[lane];
        acc.x += bf2f(p.x & 0xffffu); acc.y += bf2f(p.x >> 16);
        acc.z += bf2f(p.y & 0xffffu); acc.w += bf2f(p.y >> 16);
    }
    float ic = 1.f / (float)(c > 0 ? c : 1);
    float4 xv = ((const float4*)(x + (size_t)row * C_DIM))[lane];
    float4 r4;
    r4.x = xv.x + acc.x * ic; r4.y = xv.y + acc.y * ic;
    r4.z = xv.z + acc.z * ic; r4.w = xv.w + acc.w * ic;
    ((float4*)(x1 + (size_t)row * C_DIM))[lane] = r4;
    float s = r4.x + r4.y + r4.z + r4.w;
    float q = r4.x * r4.x + r4.y * r4.y + r4.z * r4.z + r4.w * r4.w;
    #pragma unroll
    for (int o = 32; o; o >>= 1) { s += __shfl_xor(s, o); q += __shfl_xor(q, o); }
    if (lane == 0) {
        float mm = s * (1.f / C_DIM);
        float var = q * (1.f / C_DIM) - mm * mm;
        mu[row] = mm; rs[row] = rsqrtf(var + 1e-5f);
    }
}

__global__ void bnfin_k(const float* __restrict__ hsum, const float* __restrict__ hsq,
        const float* __restrict__ bnw, const float* __restrict__ bnb,
        float* __restrict__ premul, float* __restrict__ preadd, float inv_n) {
    int c = threadIdx.x;
    float m = hsum[c] * inv_n;
    float var = hsq[c] * inv_n - m * m;
    float rstd = rsqrtf(var + 1e-5f);
    float pm = rstd * bnw[c];
    premul[c] = pm;
    preadd[c] = bnb[c] - m * pm;
}

extern "C" void kernel_launch(void* const* d_in, const int* in_sizes, int n_in,
                              void* d_out, int out_size, void* d_ws, size_t ws_size,
                              hipStream_t stream) {
    const float* x    = (const float*)d_in[0];
    const int* widx   = (const int*)d_in[1];
    const float* ln1w = (const float*)d_in[3];
    const float* ln1b = (const float*)d_in[4];
    const float* wqkv = (const float*)d_in[5];
    const float* wproj = (const float*)d_in[6];
    const float* bproj = (const float*)d_in[7];
    const float* ln2w = (const float*)d_in[8];
    const float* ln2b = (const float*)d_in[9];
    const float* w1   = (const float*)d_in[10];
    const float* b1   = (const float*)d_in[11];
    const float* bnw  = (const float*)d_in[12];
    const float* bnb  = (const float*)d_in[13];
    const float* w2   = (const float*)d_in[14];
    const float* b2   = (const float*)d_in[15];
    float* out = (float*)d_out;

    const int N  = in_sizes[0] / C_DIM;   // 25600
    const int MW = in_sizes[1];           // M * 512
    const int M  = MW / WWIN;             // 100

    char* w = (char*)d_ws;
    size_t off = 0;
    auto alloc = [&](size_t bytes) -> void* {
        void* p = w + off;
        off += (bytes + 255) & ~(size_t)255;
        return p;
    };
    // Region A: qkv bf16 planes [24][N][32] -> out_proj bf16 [MW,256] -> h f32 [N,512]
    size_t szA = (size_t)MW * C_DIM * 4;
    void* regA = alloc(szA);
    unsigned short* qkv = (unsigned short*)regA;
    unsigned short* out_proj = (unsigned short*)regA;
    float* hbuf = (float*)regA;
    // Region B: attn_out bf16 planes [8][MW][32] -> x1 f32 [N,256]
    size_t szB = (size_t)MW * C_DIM * 2;
    void* regB = alloc(szB);
    unsigned short* attn_out = (unsigned short*)regB;
    float* x1 = (float*)regB;

    unsigned short* wqkv_bf = (unsigned short*)alloc(768 * 256 * 2);
    unsigned short* wproj_bf = (unsigned short*)alloc(256 * 256 * 2);
    unsigned short* w1_bf = (unsigned short*)alloc(512 * 256 * 2);
    unsigned short* w2_bf = (unsigned short*)alloc(256 * 512 * 2);

    float* mu0 = (float*)alloc((size_t)N * 4);
    float* rs0 = (float*)alloc((size_t)N * 4);
    float* mu1 = (float*)alloc((size_t)N * 4);
    float* rs1 = (float*)alloc((size_t)N * 4);
    int* cnt   = (int*)alloc((size_t)N * 4);
    int* inv   = (int*)alloc((size_t)N * 8);
    int* wlen  = (int*)alloc((size_t)M * 4);
    float* hsum = (float*)alloc(HID_DIM * 4);
    float* hsq  = (float*)alloc(HID_DIM * 4);
    float* premul = (float*)alloc(HID_DIM * 4);
    float* preadd = (float*)alloc(HID_DIM * 4);

    hipMemsetAsync(cnt, 0, (size_t)N * 4, stream);
    hipMemsetAsync(hsum, 0, HID_DIM * 4, stream);
    hipMemsetAsync(hsq, 0, HID_DIM * 4, stream);

    cvtw_k<<<512, 256, 0, stream>>>(wqkv, wproj, w1, w2, wqkv_bf, wproj_bf, w1_bf, w2_bf);
    rowstats_k<<<N / 4, 256, 0, stream>>>(x, mu0, rs0);
    wininv_k<<<M, 512, 0, stream>>>(widx, wlen, cnt, inv);
    // QKV = LN1(x) @ w_qkv^T, scattered to head planes [24][N][32]
    mgemm_k<256, 1, 5><<<dim3(768 / 128, N / 128), 256, 0, stream>>>(
        x, wqkv_bf, nullptr, qkv, mu0, rs0, ln1w, ln1b, nullptr, nullptr, nullptr, N, 0);
    attn_mfma_k<<<M * NHEAD, 256, 0, stream>>>(qkv, widx, wlen, attn_out, N, MW);
    // out_proj = attn @ w_proj^T + b_proj (A = head-split planes, AM = MW)
    mgemm_k<256, 4, 1><<<dim3(256 / 128, MW / 128), 256, 0, stream>>>(
        attn_out, wproj_bf, bproj, out_proj, nullptr, nullptr, nullptr, nullptr,
        nullptr, nullptr, nullptr, 256, MW);
    combine_k<<<N / 4, 256, 0, stream>>>(x, out_proj, cnt, inv, x1, mu1, rs1);
    // h = LN2(x1) @ w1^T + b1, with fused BN column stats
    mgemm_k<256, 1, 3><<<dim3(512 / 128, N / 128), 256, 0, stream>>>(
        x1, w1_bf, b1, hbuf, mu1, rs1, ln2w, ln2b, nullptr, hsum, hsq, 512, 0);
    bnfin_k<<<1, HID_DIM, 0, stream>>>(hsum, hsq, bnw, bnb, premul, preadd, 1.0f / (float)N);
    // out = x1 + relu(BN(h)) @ w2^T + b2
    mgemm_k<512, 3, 4><<<dim3(256 / 128, N / 128), 256, 0, stream>>>(
        hbuf, w2_bf, b2, out, nullptr, nullptr, premul, preadd, x1, nullptr, nullptr, 256, 0);
}

// Round 8
// 300.343 us; speedup vs baseline: 1.7383x; 1.1562x over previous
//
#include <hip/hip_runtime.h>

#define C_DIM 256
#define HID_DIM 512
#define NHEAD 8
#define DHEAD 32
#define WWIN 512

typedef __attribute__((ext_vector_type(8))) short frag_ab;   // 8 bf16
typedef __attribute__((ext_vector_type(4))) short frag4;     // 4 bf16
typedef __attribute__((ext_vector_type(4))) float f32x4;

__device__ __forceinline__ float bf2f(unsigned int u16) {
    return __uint_as_float(u16 << 16);
}
__device__ __forceinline__ unsigned short f2bf(float f) {
    unsigned int x = __float_as_uint(f);
    return (unsigned short)((x + 0x7fffu + ((x >> 16) & 1u)) >> 16);
}
__device__ __forceinline__ void unpack8(uint4 u, float* d) {
    d[0] = bf2f(u.x & 0xffffu); d[1] = bf2f(u.x >> 16);
    d[2] = bf2f(u.y & 0xffffu); d[3] = bf2f(u.y >> 16);
    d[4] = bf2f(u.z & 0xffffu); d[5] = bf2f(u.z >> 16);
    d[6] = bf2f(u.w & 0xffffu); d[7] = bf2f(u.w >> 16);
}
// pack two f32 into two rounded bf16 in one v_perm
__device__ __forceinline__ unsigned int pk2(float lo, float hi) {
    return __builtin_amdgcn_perm(__float_as_uint(hi), __float_as_uint(lo), 0x07060302u);
}
// async 16B global->LDS (dest = uniform base + lane*16)
__device__ __forceinline__ void async_cp16(const void* g, void* l) {
    __builtin_amdgcn_global_load_lds(
        (const __attribute__((address_space(1))) unsigned int*)g,
        (__attribute__((address_space(3))) unsigned int*)l, 16, 0, 0);
}

// ---- per-row LayerNorm stats: one wave per row of 256 floats ----
__global__ __launch_bounds__(256) void rowstats_k(const float* __restrict__ X,
        float* __restrict__ mu, float* __restrict__ rs) {
    int lane = threadIdx.x & 63;
    int row = blockIdx.x * 4 + (threadIdx.x >> 6);
    float4 v = ((const float4*)(X + (size_t)row * C_DIM))[lane];
    float s = v.x + v.y + v.z + v.w;
    float q = v.x * v.x + v.y * v.y + v.z * v.z + v.w * v.w;
    #pragma unroll
    for (int o = 32; o; o >>= 1) { s += __shfl_xor(s, o); q += __shfl_xor(q, o); }
    if (lane == 0) {
        float m = s * (1.0f / C_DIM);
        float var = q * (1.0f / C_DIM) - m * m;
        mu[row] = m; rs[row] = rsqrtf(var + 1e-5f);
    }
}

// ---- window valid-lengths + inverse (token -> (window,offset)) map ----
__global__ __launch_bounds__(512) void wininv_k(const int* __restrict__ widx,
        int* __restrict__ wlen, int* __restrict__ cnt, int* __restrict__ inv) {
    int m = blockIdx.x, j = threadIdx.x;
    int id = widx[m * WWIN + j];
    int valid = (j == 0) || (id != widx[m * WWIN + j - 1]);
    __shared__ int part[8];
    int v = valid;
    #pragma unroll
    for (int o = 32; o; o >>= 1) v += __shfl_xor(v, o);
    if ((j & 63) == 0) part[j >> 6] = v;
    __syncthreads();
    if (j == 0) {
        int s = 0;
        #pragma unroll
        for (int i = 0; i < 8; i++) s += part[i];
        wlen[m] = s;
    }
    if (valid) {
        int slot = atomicAdd(&cnt[id], 1);
        if (slot < 2) inv[id * 2 + slot] = m * WWIN + j;
    }
}

// ---- convert the four weight matrices fp32 -> bf16 (one dispatch) ----
__global__ __launch_bounds__(256) void cvtw_k(
        const float* __restrict__ a, const float* __restrict__ b,
        const float* __restrict__ c, const float* __restrict__ d,
        unsigned short* __restrict__ oa, unsigned short* __restrict__ ob,
        unsigned short* __restrict__ oc, unsigned short* __restrict__ od) {
    int bi = blockIdx.x;
    const float* src; unsigned short* dst; int base;
    if (bi < 192)      { src = a; dst = oa; base = bi; }        // w_qkv 768x256
    else if (bi < 256) { src = b; dst = ob; base = bi - 192; }  // w_proj 256x256
    else if (bi < 384) { src = c; dst = oc; base = bi - 256; }  // w1 512x256
    else               { src = d; dst = od; base = bi - 384; }  // w2 256x512
    int i = base * 1024 + threadIdx.x * 4;
    float4 v = *(const float4*)(src + i);
    ushort4 o;
    o.x = f2bf(v.x); o.y = f2bf(v.y); o.z = f2bf(v.z); o.w = f2bf(v.w);
    *(ushort4*)(dst + i) = o;
}

// ---- MFMA GEMM: out[M,CN] = act_in(A) @ Bw[CN,K]^T (+post-ops) ----
// AMODE: 0 = bf16 A [M,K]; 4 = bf16 A head-split [K/32][M,32] (AM = A rows)
//        1 = fp32 A fused LayerNorm; 3 = fp32 A fused BN+ReLU
// OMODE: 0 = bf16; 1 = bf16 + bias; 2 = f32 + bias;
//        3 = f32 + bias + column-stat atomics; 4 = f32 + bias + resid;
//        5 = bf16 to head-planes via per-wave LDS transpose (coalesced uint4)
//            NOTE (R7 bug): each lane must store 16 shorts (2x uint4) per row
//            to cover all 64 transposed cols — 1x uint4 left half the qkv
//            planes unwritten (masked on launch #1 by stale-correct d_ws).
template<int K, int AMODE, int OMODE>
__global__ __launch_bounds__(256, 3) void mgemm_k(
        const void* __restrict__ Av, const unsigned short* __restrict__ Bw,
        const float* __restrict__ bias, void* __restrict__ Outv,
        const float* __restrict__ rowmu, const float* __restrict__ rowrs,
        const float* __restrict__ colw, const float* __restrict__ colb,
        const float* __restrict__ resid, float* __restrict__ hsum,
        float* __restrict__ hsq, int CN, int AM) {
    __shared__ unsigned short As[4096];   // 128 rows x 4 slots x 8 bf16
    __shared__ unsigned short Bs[4096];
    const int t = threadIdx.x;
    const int w = t >> 6, lane = t & 63;
    const int Q = lane >> 4, n = lane & 15;
    const int r0 = blockIdx.y * 128, c0 = blockIdx.x * 128;
    const int qr0 = (w & 1) * 64, qc0 = (w >> 1) * 64;
    const f32x4 z4 = {0.f, 0.f, 0.f, 0.f};
    f32x4 acc[4][4];
    #pragma unroll
    for (int i = 0; i < 4; i++)
        #pragma unroll
        for (int j = 0; j < 4; j++) acc[i][j] = z4;

    for (int k0 = 0; k0 < K; k0 += 32) {
        if (k0) __syncthreads();
        // ---- stage B (async, swizzled dest order) ----
        #pragma unroll
        for (int i = 0; i < 2; i++) {
            int sbase = w * 128 + i * 64;
            int l = sbase + lane;
            int col = l >> 2;
            int sub = ((l & 3) - (col >> 1)) & 3;
            async_cp16(Bw + (size_t)(c0 + col) * K + k0 + sub * 8, &Bs[sbase * 8]);
        }
        // ---- stage A ----
        if constexpr (AMODE == 0 || AMODE == 4) {
            #pragma unroll
            for (int i = 0; i < 2; i++) {
                int sbase = w * 128 + i * 64;
                int l = sbase + lane;
                int row = l >> 2;
                int sub = ((l & 3) - (row >> 1)) & 3;
                const unsigned short* src;
                if constexpr (AMODE == 0)
                    src = (const unsigned short*)Av + (size_t)(r0 + row) * K + k0 + sub * 8;
                else
                    src = (const unsigned short*)Av + (size_t)k0 * AM + (size_t)(r0 + row) * 32 + sub * 8;
                async_cp16(src, &As[sbase * 8]);
            }
        } else {
            #pragma unroll
            for (int ii = 0; ii < 2; ii++) {
                int s = t + ii * 256;
                int row = s >> 2;
                int sub = ((s & 3) - (row >> 1)) & 3;
                const float* src = (const float*)Av + (size_t)(r0 + row) * K + k0 + sub * 8;
                float4 v0 = ((const float4*)src)[0];
                float4 v1 = ((const float4*)src)[1];
                float f[8] = {v0.x, v0.y, v0.z, v0.w, v1.x, v1.y, v1.z, v1.w};
                float4 cw0 = *(const float4*)(colw + k0 + sub * 8);
                float4 cw1 = *(const float4*)(colw + k0 + sub * 8 + 4);
                float4 cb0 = *(const float4*)(colb + k0 + sub * 8);
                float4 cb1 = *(const float4*)(colb + k0 + sub * 8 + 4);
                float cw[8] = {cw0.x, cw0.y, cw0.z, cw0.w, cw1.x, cw1.y, cw1.z, cw1.w};
                float cb[8] = {cb0.x, cb0.y, cb0.z, cb0.w, cb1.x, cb1.y, cb1.z, cb1.w};
                if constexpr (AMODE == 1) {
                    float rm = rowmu[r0 + row], rv = rowrs[r0 + row];
                    #pragma unroll
                    for (int j = 0; j < 8; j++) f[j] = (f[j] - rm) * rv * cw[j] + cb[j];
                } else {
                    #pragma unroll
                    for (int j = 0; j < 8; j++) f[j] = fmaxf(f[j] * cw[j] + cb[j], 0.f);
                }
                uint4 pkd;
                pkd.x = pk2(f[0], f[1]); pkd.y = pk2(f[2], f[3]);
                pkd.z = pk2(f[4], f[5]); pkd.w = pk2(f[6], f[7]);
                *(uint4*)&As[s * 8] = pkd;
            }
        }
        asm volatile("s_waitcnt vmcnt(0)" ::: "memory");
        __syncthreads();
        // ---- compute ----
        const int asub = (Q + (n >> 1)) & 3;
        frag_ab af[4], bfr[4];
        #pragma unroll
        for (int i = 0; i < 4; i++) {
            af[i]  = *(const frag_ab*)&As[((qr0 + i * 16 + n) * 4 + asub) * 8];
            bfr[i] = *(const frag_ab*)&Bs[((qc0 + i * 16 + n) * 4 + asub) * 8];
        }
        #pragma unroll
        for (int rt = 0; rt < 4; rt++)
            #pragma unroll
            for (int ct = 0; ct < 4; ct++)
                acc[rt][ct] = __builtin_amdgcn_mfma_f32_16x16x32_bf16(
                    af[rt], bfr[ct], acc[rt][ct], 0, 0, 0);
    }

    // ---- epilogue ----
    if constexpr (OMODE == 5) {
        // per-wave LDS transpose -> coalesced uint4 stores to head planes
        __shared__ unsigned short Ts[4][16 * 72];   // 144B rows (16B-aligned)
        unsigned short* tb = Ts[w];
        #pragma unroll
        for (int rt = 0; rt < 4; rt++) {
            #pragma unroll
            for (int ct = 0; ct < 4; ct++) {
                f32x4 a = acc[rt][ct];
                #pragma unroll
                for (int i = 0; i < 4; i++)
                    tb[(Q * 4 + i) * 72 + ct * 16 + n] = f2bf(a[i]);
            }
            int r2 = lane >> 2, sg = lane & 3;
            uint4 v0 = *(const uint4*)&tb[r2 * 72 + sg * 16];
            uint4 v1 = *(const uint4*)&tb[r2 * 72 + sg * 16 + 8];
            int mrow = r0 + qr0 + rt * 16 + r2;
            int ccb = c0 + qc0 + sg * 16;
            int plane = ((ccb >> 8) << 3) | ((ccb >> 5) & 7);
            unsigned short* dst = (unsigned short*)Outv +
                ((size_t)plane * CN + mrow) * 32 + (ccb & 31);
            *(uint4*)dst = v0;
            *(uint4*)(dst + 8) = v1;
        }
        return;
    }
    float sc[4] = {0.f, 0.f, 0.f, 0.f}, qc[4] = {0.f, 0.f, 0.f, 0.f};
    #pragma unroll
    for (int rt = 0; rt < 4; rt++) {
        #pragma unroll
        for (int ct = 0; ct < 4; ct++) {
            int mrow = r0 + qr0 + rt * 16 + Q * 4;
            int ccol = c0 + qc0 + ct * 16 + n;
            f32x4 a = acc[rt][ct];
            if constexpr (OMODE == 0) {
                unsigned short* dst = (unsigned short*)Outv + (size_t)mrow * CN + ccol;
                #pragma unroll
                for (int i = 0; i < 4; i++) dst[(size_t)i * CN] = f2bf(a[i]);
            } else if constexpr (OMODE == 1) {
                float bb = bias[ccol];
                unsigned short* dst = (unsigned short*)Outv + (size_t)mrow * CN + ccol;
                #pragma unroll
                for (int i = 0; i < 4; i++) dst[(size_t)i * CN] = f2bf(a[i] + bb);
            } else if constexpr (OMODE == 2) {
                float bb = bias[ccol];
                float* dst = (float*)Outv + (size_t)mrow * CN + ccol;
                #pragma unroll
                for (int i = 0; i < 4; i++) dst[(size_t)i * CN] = a[i] + bb;
            } else if constexpr (OMODE == 3) {
                float bb = bias[ccol];
                float* dst = (float*)Outv + (size_t)mrow * CN + ccol;
                #pragma unroll
                for (int i = 0; i < 4; i++) {
                    float v = a[i] + bb;
                    dst[(size_t)i * CN] = v;
                    sc[ct] += v; qc[ct] += v * v;
                }
            } else {
                float bb = bias[ccol];
                float* dst = (float*)Outv + (size_t)mrow * CN + ccol;
                const float* rr = resid + (size_t)mrow * CN + ccol;
                #pragma unroll
                for (int i = 0; i < 4; i++) dst[(size_t)i * CN] = a[i] + bb + rr[(size_t)i * CN];
            }
        }
    }
    if constexpr (OMODE == 3) {
        #pragma unroll
        for (int ct = 0; ct < 4; ct++) {
            float s = sc[ct], q2 = qc[ct];
            s += __shfl_xor(s, 16); s += __shfl_xor(s, 32);
            q2 += __shfl_xor(q2, 16); q2 += __shfl_xor(q2, 32);
            if (Q == 0) {
                int ccol = c0 + qc0 + ct * 16 + n;
                atomicAdd(&hsum[ccol], s);
                atomicAdd(&hsq[ccol], q2);
            }
        }
    }
}

// ---- MFMA windowed attention, head-separated planes, 64 q-rows/wave ----
// Block = (window m, head h, q-half), 4 waves x 64 q rows. Grid = M*8*2.
// qf[4]/Ot[2][4] keep VGPR ~<100; __launch_bounds__(256,4) caps at 128
// (R5 lesson: never cap below need). Register-resident P via 16x16x16 PV.
// aout written through a per-wave LDS transpose -> full-line uint4 stores.
#define KSTR 40    // K row stride in shorts (32 + 8 pad)
#define VSTR 136   // V^T row stride in shorts (128 + 8 pad)
#define TSTR 40    // aout transpose row stride in shorts (80B, 16B-aligned)
__global__ __launch_bounds__(256, 4) void attn_mfma_k(
        const unsigned short* __restrict__ qkv, const int* __restrict__ widx,
        const int* __restrict__ wlen, unsigned short* __restrict__ aout,
        int N, int MW) {
    __shared__ unsigned short Kl[128 * KSTR];
    __shared__ unsigned short Vt[32 * VSTR];
    __shared__ unsigned short Ts[4][16 * TSTR];
    const int mh = blockIdx.x >> 1, half = blockIdx.x & 1;
    const int m = mh >> 3, h = mh & 7;
    const int len = wlen[m];
    if (half && len <= 256) return;      // q rows 256.. are all padding
    const int t = threadIdx.x;
    const int w = t >> 6, lane = t & 63;
    const int Q = lane >> 4, n = lane & 15;
    const int qbase = half * 256 + w * 64;
    const int* wrow = widx + m * WWIN;
    const unsigned short* Qp = qkv + (size_t)h * N * 32;
    const unsigned short* Kp = qkv + (size_t)(8 + h) * N * 32;
    const unsigned short* Vp = qkv + (size_t)(16 + h) * N * 32;
    const f32x4 z4 = {0.f, 0.f, 0.f, 0.f};

    // Q fragments (4 q-tiles), pre-scaled by 1/sqrt(DH) * log2(e)
    const float qs = 0.17677669529663687f * 1.4426950408889634f;
    frag_ab qf[4];
    #pragma unroll
    for (int qt = 0; qt < 4; qt++) {
        int tok = wrow[qbase + qt * 16 + n];
        uint4 u = *(const uint4*)(Qp + (size_t)tok * 32 + Q * 8);
        float f[8]; unpack8(u, f);
        uint4 r;
        r.x = pk2(f[0] * qs, f[1] * qs); r.y = pk2(f[2] * qs, f[3] * qs);
        r.z = pk2(f[4] * qs, f[5] * qs); r.w = pk2(f[6] * qs, f[7] * qs);
        qf[qt] = __builtin_bit_cast(frag_ab, r);
    }

    f32x4 Ot[2][4];
    #pragma unroll
    for (int dt = 0; dt < 2; dt++)
        #pragma unroll
        for (int qt = 0; qt < 4; qt++) Ot[dt][qt] = z4;
    float rsum[4] = {0.f, 0.f, 0.f, 0.f};

    const int nchunk = (len + 127) >> 7;
    for (int c = 0; c < nchunk; c++) {
        const int kb = c << 7;
        __syncthreads();
        if (t < 128) {                       // stage V^T (transposed scatter)
            int r = t;
            int tok = wrow[kb + r];
            const uint4* src = (const uint4*)(Vp + (size_t)tok * 32);
            #pragma unroll
            for (int i = 0; i < 4; i++) {
                uint4 u = src[i];
                unsigned short* vp = &Vt[(i * 8) * VSTR + r];
                vp[0 * VSTR] = (unsigned short)(u.x & 0xffffu);
                vp[1 * VSTR] = (unsigned short)(u.x >> 16);
                vp[2 * VSTR] = (unsigned short)(u.y & 0xffffu);
                vp[3 * VSTR] = (unsigned short)(u.y >> 16);
                vp[4 * VSTR] = (unsigned short)(u.z & 0xffffu);
                vp[5 * VSTR] = (unsigned short)(u.z >> 16);
                vp[6 * VSTR] = (unsigned short)(u.w & 0xffffu);
                vp[7 * VSTR] = (unsigned short)(u.w >> 16);
            }
        } else {                             // stage K rows (rotated, padded)
            int r = t - 128;
            int tok = wrow[kb + r];
            const uint4* src = (const uint4*)(Kp + (size_t)tok * 32);
            #pragma unroll
            for (int i = 0; i < 4; i++) {
                int c4 = (r + i) & 3;
                *(uint4*)&Kl[r * KSTR + c4 * 8] = src[c4];
            }
        }
        __syncthreads();
        int rem = len - kb; if (rem > 128) rem = 128;
        const int nsub = (rem + 31) >> 5;
        for (int s = 0; s < nsub; s++) {
            const int lim = rem - s * 32;
            frag_ab kf0 = *(const frag_ab*)&Kl[(s * 32 + n) * KSTR + Q * 8];
            frag_ab kf1 = *(const frag_ab*)&Kl[(s * 32 + 16 + n) * KSTR + Q * 8];
            frag4 va00 = *(const frag4*)&Vt[n * VSTR + s * 32 + 4 * Q];
            frag4 va01 = *(const frag4*)&Vt[n * VSTR + s * 32 + 16 + 4 * Q];
            frag4 va10 = *(const frag4*)&Vt[(16 + n) * VSTR + s * 32 + 4 * Q];
            frag4 va11 = *(const frag4*)&Vt[(16 + n) * VSTR + s * 32 + 16 + 4 * Q];
            #pragma unroll
            for (int qt = 0; qt < 4; qt++) {
                f32x4 s0 = __builtin_amdgcn_mfma_f32_16x16x32_bf16(kf0, qf[qt], z4, 0, 0, 0);
                f32x4 s1 = __builtin_amdgcn_mfma_f32_16x16x32_bf16(kf1, qf[qt], z4, 0, 0, 0);
                float e[8];
                #pragma unroll
                for (int i = 0; i < 4; i++) {
                    e[i]     = __builtin_amdgcn_exp2f(s0[i]);
                    e[4 + i] = __builtin_amdgcn_exp2f(s1[i]);
                }
                if (lim < 32) {
                    #pragma unroll
                    for (int i = 0; i < 4; i++) {
                        if (4 * Q + i >= lim)      e[i] = 0.f;
                        if (16 + 4 * Q + i >= lim) e[4 + i] = 0.f;
                    }
                }
                float rsq = rsum[qt];
                #pragma unroll
                for (int i = 0; i < 8; i++) rsq += e[i];
                rsum[qt] = rsq;
                uint2 u0, u1;
                u0.x = pk2(e[0], e[1]); u0.y = pk2(e[2], e[3]);
                u1.x = pk2(e[4], e[5]); u1.y = pk2(e[6], e[7]);
                frag4 p0 = __builtin_bit_cast(frag4, u0);
                frag4 p1 = __builtin_bit_cast(frag4, u1);
                Ot[0][qt] = __builtin_amdgcn_mfma_f32_16x16x16bf16_1k(va00, p0, Ot[0][qt], 0, 0, 0);
                Ot[0][qt] = __builtin_amdgcn_mfma_f32_16x16x16bf16_1k(va01, p1, Ot[0][qt], 0, 0, 0);
                Ot[1][qt] = __builtin_amdgcn_mfma_f32_16x16x16bf16_1k(va10, p0, Ot[1][qt], 0, 0, 0);
                Ot[1][qt] = __builtin_amdgcn_mfma_f32_16x16x16bf16_1k(va11, p1, Ot[1][qt], 0, 0, 0);
            }
        }
    }

    // epilogue: normalize, per-wave LDS transpose, coalesced 16B stores
    unsigned short* tb = Ts[w];
    const int r2 = lane >> 2, sg = lane & 3;
    #pragma unroll
    for (int qt = 0; qt < 4; qt++) {
        float r = rsum[qt];
        r += __shfl_xor(r, 16);
        r += __shfl_xor(r, 32);
        float inv = 1.f / r;
        #pragma unroll
        for (int dt = 0; dt < 2; dt++) {
            f32x4 o = Ot[dt][qt];
            uint2 pk;
            pk.x = pk2(o[0] * inv, o[1] * inv);
            pk.y = pk2(o[2] * inv, o[3] * inv);
            *(uint2*)&tb[n * TSTR + dt * 16 + 4 * Q] = pk;
        }
        uint4 v = *(const uint4*)&tb[r2 * TSTR + sg * 8];
        unsigned short* dst = aout +
            ((size_t)h * MW + (size_t)(m * WWIN + qbase + qt * 16 + r2)) * 32 + sg * 8;
        *(uint4*)dst = v;
    }
}

// ---- combine: x1 = x + gathered(out_proj bf16)/count, plus LN2 row stats ----
__global__ __launch_bounds__(256) void combine_k(
        const float* __restrict__ x, const unsigned short* __restrict__ proj,
        const int* __restrict__ cnt, const int* __restrict__ inv,
        float* __restrict__ x1, float* __restrict__ mu, float* __restrict__ rs) {
    int lane = threadIdx.x & 63;
    int row = blockIdx.x * 4 + (threadIdx.x >> 6);
    int c = cnt[row];
    if (c > 2) c = 2;
    float4 acc = make_float4(0.f, 0.f, 0.f, 0.f);
    for (int s = 0; s < c; s++) {
        int src = inv[row * 2 + s];
        uint2 p = ((const uint2*)(proj + (size_t)src * C_DIM))[lane];
        acc.x += bf2f(p.x & 0xffffu); acc.y += bf2f(p.x >> 16);
        acc.z += bf2f(p.y & 0xffffu); acc.w += bf2f(p.y >> 16);
    }
    float ic = 1.f / (float)(c > 0 ? c : 1);
    float4 xv = ((const float4*)(x + (size_t)row * C_DIM))[lane];
    float4 r4;
    r4.x = xv.x + acc.x * ic; r4.y = xv.y + acc.y * ic;
    r4.z = xv.z + acc.z * ic; r4.w = xv.w + acc.w * ic;
    ((float4*)(x1 + (size_t)row * C_DIM))[lane] = r4;
    float s = r4.x + r4.y + r4.z + r4.w;
    float q = r4.x * r4.x + r4.y * r4.y + r4.z * r4.z + r4.w * r4.w;
    #pragma unroll
    for (int o = 32; o; o >>= 1) { s += __shfl_xor(s, o); q += __shfl_xor(q, o); }
    if (lane == 0) {
        float mm = s * (1.f / C_DIM);
        float var = q * (1.f / C_DIM) - mm * mm;
        mu[row] = mm; rs[row] = rsqrtf(var + 1e-5f);
    }
}

__global__ void bnfin_k(const float* __restrict__ hsum, const float* __restrict__ hsq,
        const float* __restrict__ bnw, const float* __restrict__ bnb,
        float* __restrict__ premul, float* __restrict__ preadd, float inv_n) {
    int c = threadIdx.x;
    float m = hsum[c] * inv_n;
    float var = hsq[c] * inv_n - m * m;
    float rstd = rsqrtf(var + 1e-5f);
    float pm = rstd * bnw[c];
    premul[c] = pm;
    preadd[c] = bnb[c] - m * pm;
}

extern "C" void kernel_launch(void* const* d_in, const int* in_sizes, int n_in,
                              void* d_out, int out_size, void* d_ws, size_t ws_size,
                              hipStream_t stream) {
    const float* x    = (const float*)d_in[0];
    const int* widx   = (const int*)d_in[1];
    const float* ln1w = (const float*)d_in[3];
    const float* ln1b = (const float*)d_in[4];
    const float* wqkv = (const float*)d_in[5];
    const float* wproj = (const float*)d_in[6];
    const float* bproj = (const float*)d_in[7];
    const float* ln2w = (const float*)d_in[8];
    const float* ln2b = (const float*)d_in[9];
    const float* w1   = (const float*)d_in[10];
    const float* b1   = (const float*)d_in[11];
    const float* bnw  = (const float*)d_in[12];
    const float* bnb  = (const float*)d_in[13];
    const float* w2   = (const float*)d_in[14];
    const float* b2   = (const float*)d_in[15];
    float* out = (float*)d_out;

    const int N  = in_sizes[0] / C_DIM;   // 25600
    const int MW = in_sizes[1];           // M * 512
    const int M  = MW / WWIN;             // 100

    char* w = (char*)d_ws;
    size_t off = 0;
    auto alloc = [&](size_t bytes) -> void* {
        void* p = w + off;
        off += (bytes + 255) & ~(size_t)255;
        return p;
    };
    // Region A: qkv bf16 planes [24][N][32] -> out_proj bf16 [MW,256] -> h f32 [N,512]
    size_t szA = (size_t)MW * C_DIM * 4;
    void* regA = alloc(szA);
    unsigned short* qkv = (unsigned short*)regA;
    unsigned short* out_proj = (unsigned short*)regA;
    float* hbuf = (float*)regA;
    // Region B: attn_out bf16 planes [8][MW][32] -> x1 f32 [N,256]
    size_t szB = (size_t)MW * C_DIM * 2;
    void* regB = alloc(szB);
    unsigned short* attn_out = (unsigned short*)regB;
    float* x1 = (float*)regB;

    unsigned short* wqkv_bf = (unsigned short*)alloc(768 * 256 * 2);
    unsigned short* wproj_bf = (unsigned short*)alloc(256 * 256 * 2);
    unsigned short* w1_bf = (unsigned short*)alloc(512 * 256 * 2);
    unsigned short* w2_bf = (unsigned short*)alloc(256 * 512 * 2);

    float* mu0 = (float*)alloc((size_t)N * 4);
    float* rs0 = (float*)alloc((size_t)N * 4);
    float* mu1 = (float*)alloc((size_t)N * 4);
    float* rs1 = (float*)alloc((size_t)N * 4);
    int* cnt   = (int*)alloc((size_t)N * 4);
    int* inv   = (int*)alloc((size_t)N * 8);
    int* wlen  = (int*)alloc((size_t)M * 4);
    float* hsum = (float*)alloc(HID_DIM * 4);
    float* hsq  = (float*)alloc(HID_DIM * 4);
    float* premul = (float*)alloc(HID_DIM * 4);
    float* preadd = (float*)alloc(HID_DIM * 4);

    hipMemsetAsync(cnt, 0, (size_t)N * 4, stream);
    hipMemsetAsync(hsum, 0, HID_DIM * 4, stream);
    hipMemsetAsync(hsq, 0, HID_DIM * 4, stream);

    cvtw_k<<<512, 256, 0, stream>>>(wqkv, wproj, w1, w2, wqkv_bf, wproj_bf, w1_bf, w2_bf);
    rowstats_k<<<N / 4, 256, 0, stream>>>(x, mu0, rs0);
    wininv_k<<<M, 512, 0, stream>>>(widx, wlen, cnt, inv);
    // QKV = LN1(x) @ w_qkv^T, scattered to head planes [24][N][32]
    mgemm_k<256, 1, 5><<<dim3(768 / 128, N / 128), 256, 0, stream>>>(
        x, wqkv_bf, nullptr, qkv, mu0, rs0, ln1w, ln1b, nullptr, nullptr, nullptr, N, 0);
    attn_mfma_k<<<M * NHEAD * 2, 256, 0, stream>>>(qkv, widx, wlen, attn_out, N, MW);
    // out_proj = attn @ w_proj^T + b_proj (A = head-split planes, AM = MW)
    mgemm_k<256, 4, 1><<<dim3(256 / 128, MW / 128), 256, 0, stream>>>(
        attn_out, wproj_bf, bproj, out_proj, nullptr, nullptr, nullptr, nullptr,
        nullptr, nullptr, nullptr, 256, MW);
    combine_k<<<N / 4, 256, 0, stream>>>(x, out_proj, cnt, inv, x1, mu1, rs1);
    // h = LN2(x1) @ w1^T + b1, with fused BN column stats
    mgemm_k<256, 1, 3><<<dim3(512 / 128, N / 128), 256, 0, stream>>>(
        x1, w1_bf, b1, hbuf, mu1, rs1, ln2w, ln2b, nullptr, hsum, hsq, 512, 0);
    bnfin_k<<<1, HID_DIM, 0, stream>>>(hsum, hsq, bnw, bnb, premul, preadd, 1.0f / (float)N);
    // out = x1 + relu(BN(h)) @ w2^T + b2
    mgemm_k<512, 3, 4><<<dim3(256 / 128, N / 128), 256, 0, stream>>>(
        hbuf, w2_bf, b2, out, nullptr, nullptr, premul, preadd, x1, nullptr, nullptr, 256, 0);
}

// Round 9
// 273.666 us; speedup vs baseline: 1.9077x; 1.0975x over previous
//
#include <hip/hip_runtime.h>

#define C_DIM 256
#define HID_DIM 512
#define NHEAD 8
#define DHEAD 32
#define WWIN 512

typedef __attribute__((ext_vector_type(8))) short frag_ab;   // 8 bf16
typedef __attribute__((ext_vector_type(4))) short frag4;     // 4 bf16
typedef __attribute__((ext_vector_type(4))) float f32x4;

__device__ __forceinline__ float bf2f(unsigned int u16) {
    return __uint_as_float(u16 << 16);
}
__device__ __forceinline__ unsigned short f2bf(float f) {
    unsigned int x = __float_as_uint(f);
    return (unsigned short)((x + 0x7fffu + ((x >> 16) & 1u)) >> 16);
}
__device__ __forceinline__ void unpack8(uint4 u, float* d) {
    d[0] = bf2f(u.x & 0xffffu); d[1] = bf2f(u.x >> 16);
    d[2] = bf2f(u.y & 0xffffu); d[3] = bf2f(u.y >> 16);
    d[4] = bf2f(u.z & 0xffffu); d[5] = bf2f(u.z >> 16);
    d[6] = bf2f(u.w & 0xffffu); d[7] = bf2f(u.w >> 16);
}
// pack two f32 into two rounded bf16 in one v_perm
__device__ __forceinline__ unsigned int pk2(float lo, float hi) {
    return __builtin_amdgcn_perm(__float_as_uint(hi), __float_as_uint(lo), 0x07060302u);
}
// async 16B global->LDS (dest = uniform base + lane*16)
__device__ __forceinline__ void async_cp16(const void* g, void* l) {
    __builtin_amdgcn_global_load_lds(
        (const __attribute__((address_space(1))) unsigned int*)g,
        (__attribute__((address_space(3))) unsigned int*)l, 16, 0, 0);
}

// ---- LN1: normalize x rows, write bf16 (one wave per row) ----
__global__ __launch_bounds__(256) void ln1_k(const float* __restrict__ X,
        const float* __restrict__ wv, const float* __restrict__ bv,
        unsigned short* __restrict__ out) {
    int lane = threadIdx.x & 63;
    int row = blockIdx.x * 4 + (threadIdx.x >> 6);
    float4 v = ((const float4*)(X + (size_t)row * C_DIM))[lane];
    float s = v.x + v.y + v.z + v.w;
    float q = v.x * v.x + v.y * v.y + v.z * v.z + v.w * v.w;
    #pragma unroll
    for (int o = 32; o; o >>= 1) { s += __shfl_xor(s, o); q += __shfl_xor(q, o); }
    float mm = s * (1.f / C_DIM);
    float rv = rsqrtf(q * (1.f / C_DIM) - mm * mm + 1e-5f);
    float4 w4 = ((const float4*)wv)[lane];
    float4 b4 = ((const float4*)bv)[lane];
    uint2 o2;
    o2.x = pk2((v.x - mm) * rv * w4.x + b4.x, (v.y - mm) * rv * w4.y + b4.y);
    o2.y = pk2((v.z - mm) * rv * w4.z + b4.z, (v.w - mm) * rv * w4.w + b4.w);
    ((uint2*)(out + (size_t)row * C_DIM))[lane] = o2;
}

// ---- window valid-lengths + inverse (token -> (window,offset)) map ----
__global__ __launch_bounds__(512) void wininv_k(const int* __restrict__ widx,
        int* __restrict__ wlen, int* __restrict__ cnt, int* __restrict__ inv) {
    int m = blockIdx.x, j = threadIdx.x;
    int id = widx[m * WWIN + j];
    int valid = (j == 0) || (id != widx[m * WWIN + j - 1]);
    __shared__ int part[8];
    int v = valid;
    #pragma unroll
    for (int o = 32; o; o >>= 1) v += __shfl_xor(v, o);
    if ((j & 63) == 0) part[j >> 6] = v;
    __syncthreads();
    if (j == 0) {
        int s = 0;
        #pragma unroll
        for (int i = 0; i < 8; i++) s += part[i];
        wlen[m] = s;
    }
    if (valid) {
        int slot = atomicAdd(&cnt[id], 1);
        if (slot < 2) inv[id * 2 + slot] = m * WWIN + j;
    }
}

// ---- convert the four weight matrices fp32 -> bf16 (one dispatch) ----
__global__ __launch_bounds__(256) void cvtw_k(
        const float* __restrict__ a, const float* __restrict__ b,
        const float* __restrict__ c, const float* __restrict__ d,
        unsigned short* __restrict__ oa, unsigned short* __restrict__ ob,
        unsigned short* __restrict__ oc, unsigned short* __restrict__ od) {
    int bi = blockIdx.x;
    const float* src; unsigned short* dst; int base;
    if (bi < 192)      { src = a; dst = oa; base = bi; }        // w_qkv 768x256
    else if (bi < 256) { src = b; dst = ob; base = bi - 192; }  // w_proj 256x256
    else if (bi < 384) { src = c; dst = oc; base = bi - 256; }  // w1 512x256
    else               { src = d; dst = od; base = bi - 384; }  // w2 256x512
    int i = base * 1024 + threadIdx.x * 4;
    float4 v = *(const float4*)(src + i);
    ushort4 o;
    o.x = f2bf(v.x); o.y = f2bf(v.y); o.z = f2bf(v.z); o.w = f2bf(v.w);
    *(ushort4*)(dst + i) = o;
}

// ---- MFMA GEMM: out[M,CN] = act_in(A) @ Bw[CN,K]^T (+post-ops) ----
// AMODE: 0 = bf16 A [M,K] via global_load_lds
//        4 = bf16 A head-split [K/32][M,32] via global_load_lds (AM = A rows)
//        2 = bf16 A [M,K] + fused affine+relu: relu(a*colw[k]+colb[k])
// OMODE: 4 = f32 + bias + resid
//        5 = bf16 to head-planes via per-wave LDS transpose (coalesced)
//        6 = bf16 row-major via transpose + bias + column-stat atomics
//        7 = bf16 row-major via transpose + bias
template<int K, int AMODE, int OMODE>
__global__ __launch_bounds__(256, 3) void mgemm_k(
        const void* __restrict__ Av, const unsigned short* __restrict__ Bw,
        const float* __restrict__ bias, void* __restrict__ Outv,
        const float* __restrict__ colw, const float* __restrict__ colb,
        const float* __restrict__ resid, float* __restrict__ hsum,
        float* __restrict__ hsq, int CN, int AM) {
    __shared__ unsigned short As[4096];   // 128 rows x 4 slots x 8 bf16
    __shared__ unsigned short Bs[4096];
    const int t = threadIdx.x;
    const int w = t >> 6, lane = t & 63;
    const int Q = lane >> 4, n = lane & 15;
    const int r0 = blockIdx.y * 128, c0 = blockIdx.x * 128;
    const int qr0 = (w & 1) * 64, qc0 = (w >> 1) * 64;
    const f32x4 z4 = {0.f, 0.f, 0.f, 0.f};
    f32x4 acc[4][4];
    #pragma unroll
    for (int i = 0; i < 4; i++)
        #pragma unroll
        for (int j = 0; j < 4; j++) acc[i][j] = z4;

    for (int k0 = 0; k0 < K; k0 += 32) {
        if (k0) __syncthreads();
        // ---- stage B (async, swizzled dest order) ----
        #pragma unroll
        for (int i = 0; i < 2; i++) {
            int sbase = w * 128 + i * 64;
            int l = sbase + lane;
            int col = l >> 2;
            int sub = ((l & 3) - (col >> 1)) & 3;
            async_cp16(Bw + (size_t)(c0 + col) * K + k0 + sub * 8, &Bs[sbase * 8]);
        }
        // ---- stage A ----
        if constexpr (AMODE == 0 || AMODE == 4) {
            #pragma unroll
            for (int i = 0; i < 2; i++) {
                int sbase = w * 128 + i * 64;
                int l = sbase + lane;
                int row = l >> 2;
                int sub = ((l & 3) - (row >> 1)) & 3;
                const unsigned short* src;
                if constexpr (AMODE == 0)
                    src = (const unsigned short*)Av + (size_t)(r0 + row) * K + k0 + sub * 8;
                else
                    src = (const unsigned short*)Av + (size_t)k0 * AM + (size_t)(r0 + row) * 32 + sub * 8;
                async_cp16(src, &As[sbase * 8]);
            }
        } else {  // AMODE == 2: bf16 load + affine + relu
            #pragma unroll
            for (int ii = 0; ii < 2; ii++) {
                int s = t + ii * 256;
                int row = s >> 2;
                int sub = ((s & 3) - (row >> 1)) & 3;
                uint4 u = *(const uint4*)((const unsigned short*)Av +
                        (size_t)(r0 + row) * K + k0 + sub * 8);
                float f[8]; unpack8(u, f);
                float4 cw0 = *(const float4*)(colw + k0 + sub * 8);
                float4 cw1 = *(const float4*)(colw + k0 + sub * 8 + 4);
                float4 cb0 = *(const float4*)(colb + k0 + sub * 8);
                float4 cb1 = *(const float4*)(colb + k0 + sub * 8 + 4);
                float cw[8] = {cw0.x, cw0.y, cw0.z, cw0.w, cw1.x, cw1.y, cw1.z, cw1.w};
                float cb[8] = {cb0.x, cb0.y, cb0.z, cb0.w, cb1.x, cb1.y, cb1.z, cb1.w};
                #pragma unroll
                for (int j = 0; j < 8; j++) f[j] = fmaxf(f[j] * cw[j] + cb[j], 0.f);
                uint4 pkd;
                pkd.x = pk2(f[0], f[1]); pkd.y = pk2(f[2], f[3]);
                pkd.z = pk2(f[4], f[5]); pkd.w = pk2(f[6], f[7]);
                *(uint4*)&As[s * 8] = pkd;
            }
        }
        asm volatile("s_waitcnt vmcnt(0)" ::: "memory");
        __syncthreads();
        // ---- compute ----
        const int asub = (Q + (n >> 1)) & 3;
        frag_ab af[4], bfr[4];
        #pragma unroll
        for (int i = 0; i < 4; i++) {
            af[i]  = *(const frag_ab*)&As[((qr0 + i * 16 + n) * 4 + asub) * 8];
            bfr[i] = *(const frag_ab*)&Bs[((qc0 + i * 16 + n) * 4 + asub) * 8];
        }
        #pragma unroll
        for (int rt = 0; rt < 4; rt++)
            #pragma unroll
            for (int ct = 0; ct < 4; ct++)
                acc[rt][ct] = __builtin_amdgcn_mfma_f32_16x16x32_bf16(
                    af[rt], bfr[ct], acc[rt][ct], 0, 0, 0);
    }

    // ---- epilogue ----
    if constexpr (OMODE == 5 || OMODE == 6 || OMODE == 7) {
        // per-wave LDS transpose -> coalesced 2x uint4 (16 shorts) per lane
        __shared__ unsigned short Ts[4][16 * 72];   // 144B rows (16B-aligned)
        unsigned short* tb = Ts[w];
        float sc[4] = {0.f, 0.f, 0.f, 0.f}, qc[4] = {0.f, 0.f, 0.f, 0.f};
        const int r2 = lane >> 2, sg = lane & 3;
        #pragma unroll
        for (int rt = 0; rt < 4; rt++) {
            #pragma unroll
            for (int ct = 0; ct < 4; ct++) {
                float bb = 0.f;
                if constexpr (OMODE != 5) bb = bias[c0 + qc0 + ct * 16 + n];
                f32x4 a = acc[rt][ct];
                #pragma unroll
                for (int i = 0; i < 4; i++) {
                    float v = a[i] + bb;
                    if constexpr (OMODE == 6) { sc[ct] += v; qc[ct] += v * v; }
                    tb[(Q * 4 + i) * 72 + ct * 16 + n] = f2bf(v);
                }
            }
            uint4 v0 = *(const uint4*)&tb[r2 * 72 + sg * 16];
            uint4 v1 = *(const uint4*)&tb[r2 * 72 + sg * 16 + 8];
            int mrow = r0 + qr0 + rt * 16 + r2;
            if constexpr (OMODE == 5) {
                int ccb = c0 + qc0 + sg * 16;
                int plane = ((ccb >> 8) << 3) | ((ccb >> 5) & 7);
                unsigned short* dst = (unsigned short*)Outv +
                    ((size_t)plane * CN + mrow) * 32 + (ccb & 31);
                *(uint4*)dst = v0;
                *(uint4*)(dst + 8) = v1;
            } else {
                unsigned short* dst = (unsigned short*)Outv +
                    (size_t)mrow * CN + c0 + qc0 + sg * 16;
                *(uint4*)dst = v0;
                *(uint4*)(dst + 8) = v1;
            }
        }
        if constexpr (OMODE == 6) {
            #pragma unroll
            for (int ct = 0; ct < 4; ct++) {
                float s = sc[ct], q2 = qc[ct];
                s += __shfl_xor(s, 16); s += __shfl_xor(s, 32);
                q2 += __shfl_xor(q2, 16); q2 += __shfl_xor(q2, 32);
                if (Q == 0) {
                    int ccol = c0 + qc0 + ct * 16 + n;
                    atomicAdd(&hsum[ccol], s);
                    atomicAdd(&hsq[ccol], q2);
                }
            }
        }
        return;
    }
    // OMODE == 4: f32 + bias + resid
    #pragma unroll
    for (int rt = 0; rt < 4; rt++) {
        #pragma unroll
        for (int ct = 0; ct < 4; ct++) {
            int mrow = r0 + qr0 + rt * 16 + Q * 4;
            int ccol = c0 + qc0 + ct * 16 + n;
            f32x4 a = acc[rt][ct];
            float bb = bias[ccol];
            float* dst = (float*)Outv + (size_t)mrow * CN + ccol;
            const float* rr = resid + (size_t)mrow * CN + ccol;
            #pragma unroll
            for (int i = 0; i < 4; i++) dst[(size_t)i * CN] = a[i] + bb + rr[(size_t)i * CN];
        }
    }
}

// ---- MFMA windowed attention, head-separated planes, 64 q-rows/wave ----
#define KSTR 40    // K row stride in shorts (32 + 8 pad)
#define VSTR 136   // V^T row stride in shorts (128 + 8 pad)
#define TSTR 40    // aout transpose row stride in shorts
__global__ __launch_bounds__(256, 4) void attn_mfma_k(
        const unsigned short* __restrict__ qkv, const int* __restrict__ widx,
        const int* __restrict__ wlen, unsigned short* __restrict__ aout,
        int N, int MW) {
    __shared__ unsigned short Kl[128 * KSTR];
    __shared__ unsigned short Vt[32 * VSTR];
    __shared__ unsigned short Ts[4][16 * TSTR];
    const int mh = blockIdx.x >> 1, half = blockIdx.x & 1;
    const int m = mh >> 3, h = mh & 7;
    const int len = wlen[m];
    if (half && len <= 256) return;      // q rows 256.. are all padding
    const int t = threadIdx.x;
    const int w = t >> 6, lane = t & 63;
    const int Q = lane >> 4, n = lane & 15;
    const int qbase = half * 256 + w * 64;
    const int* wrow = widx + m * WWIN;
    const unsigned short* Qp = qkv + (size_t)h * N * 32;
    const unsigned short* Kp = qkv + (size_t)(8 + h) * N * 32;
    const unsigned short* Vp = qkv + (size_t)(16 + h) * N * 32;
    const f32x4 z4 = {0.f, 0.f, 0.f, 0.f};

    const float qs = 0.17677669529663687f * 1.4426950408889634f;
    frag_ab qf[4];
    #pragma unroll
    for (int qt = 0; qt < 4; qt++) {
        int tok = wrow[qbase + qt * 16 + n];
        uint4 u = *(const uint4*)(Qp + (size_t)tok * 32 + Q * 8);
        float f[8]; unpack8(u, f);
        uint4 r;
        r.x = pk2(f[0] * qs, f[1] * qs); r.y = pk2(f[2] * qs, f[3] * qs);
        r.z = pk2(f[4] * qs, f[5] * qs); r.w = pk2(f[6] * qs, f[7] * qs);
        qf[qt] = __builtin_bit_cast(frag_ab, r);
    }

    f32x4 Ot[2][4];
    #pragma unroll
    for (int dt = 0; dt < 2; dt++)
        #pragma unroll
        for (int qt = 0; qt < 4; qt++) Ot[dt][qt] = z4;
    float rsum[4] = {0.f, 0.f, 0.f, 0.f};

    const int nchunk = (len + 127) >> 7;
    for (int c = 0; c < nchunk; c++) {
        const int kb = c << 7;
        __syncthreads();
        if (t < 128) {                       // stage V^T (transposed scatter)
            int r = t;
            int tok = wrow[kb + r];
            const uint4* src = (const uint4*)(Vp + (size_t)tok * 32);
            #pragma unroll
            for (int i = 0; i < 4; i++) {
                uint4 u = src[i];
                unsigned short* vp = &Vt[(i * 8) * VSTR + r];
                vp[0 * VSTR] = (unsigned short)(u.x & 0xffffu);
                vp[1 * VSTR] = (unsigned short)(u.x >> 16);
                vp[2 * VSTR] = (unsigned short)(u.y & 0xffffu);
                vp[3 * VSTR] = (unsigned short)(u.y >> 16);
                vp[4 * VSTR] = (unsigned short)(u.z & 0xffffu);
                vp[5 * VSTR] = (unsigned short)(u.z >> 16);
                vp[6 * VSTR] = (unsigned short)(u.w & 0xffffu);
                vp[7 * VSTR] = (unsigned short)(u.w >> 16);
            }
        } else {                             // stage K rows (rotated, padded)
            int r = t - 128;
            int tok = wrow[kb + r];
            const uint4* src = (const uint4*)(Kp + (size_t)tok * 32);
            #pragma unroll
            for (int i = 0; i < 4; i++) {
                int c4 = (r + i) & 3;
                *(uint4*)&Kl[r * KSTR + c4 * 8] = src[c4];
            }
        }
        __syncthreads();
        int rem = len - kb; if (rem > 128) rem = 128;
        const int nsub = (rem + 31) >> 5;
        for (int s = 0; s < nsub; s++) {
            const int lim = rem - s * 32;
            frag_ab kf0 = *(const frag_ab*)&Kl[(s * 32 + n) * KSTR + Q * 8];
            frag_ab kf1 = *(const frag_ab*)&Kl[(s * 32 + 16 + n) * KSTR + Q * 8];
            frag4 va00 = *(const frag4*)&Vt[n * VSTR + s * 32 + 4 * Q];
            frag4 va01 = *(const frag4*)&Vt[n * VSTR + s * 32 + 16 + 4 * Q];
            frag4 va10 = *(const frag4*)&Vt[(16 + n) * VSTR + s * 32 + 4 * Q];
            frag4 va11 = *(const frag4*)&Vt[(16 + n) * VSTR + s * 32 + 16 + 4 * Q];
            #pragma unroll
            for (int qt = 0; qt < 4; qt++) {
                f32x4 s0 = __builtin_amdgcn_mfma_f32_16x16x32_bf16(kf0, qf[qt], z4, 0, 0, 0);
                f32x4 s1 = __builtin_amdgcn_mfma_f32_16x16x32_bf16(kf1, qf[qt], z4, 0, 0, 0);
                float e[8];
                #pragma unroll
                for (int i = 0; i < 4; i++) {
                    e[i]     = __builtin_amdgcn_exp2f(s0[i]);
                    e[4 + i] = __builtin_amdgcn_exp2f(s1[i]);
                }
                if (lim < 32) {
                    #pragma unroll
                    for (int i = 0; i < 4; i++) {
                        if (4 * Q + i >= lim)      e[i] = 0.f;
                        if (16 + 4 * Q + i >= lim) e[4 + i] = 0.f;
                    }
                }
                float rsq = rsum[qt];
                #pragma unroll
                for (int i = 0; i < 8; i++) rsq += e[i];
                rsum[qt] = rsq;
                uint2 u0, u1;
                u0.x = pk2(e[0], e[1]); u0.y = pk2(e[2], e[3]);
                u1.x = pk2(e[4], e[5]); u1.y = pk2(e[6], e[7]);
                frag4 p0 = __builtin_bit_cast(frag4, u0);
                frag4 p1 = __builtin_bit_cast(frag4, u1);
                Ot[0][qt] = __builtin_amdgcn_mfma_f32_16x16x16bf16_1k(va00, p0, Ot[0][qt], 0, 0, 0);
                Ot[0][qt] = __builtin_amdgcn_mfma_f32_16x16x16bf16_1k(va01, p1, Ot[0][qt], 0, 0, 0);
                Ot[1][qt] = __builtin_amdgcn_mfma_f32_16x16x16bf16_1k(va10, p0, Ot[1][qt], 0, 0, 0);
                Ot[1][qt] = __builtin_amdgcn_mfma_f32_16x16x16bf16_1k(va11, p1, Ot[1][qt], 0, 0, 0);
            }
        }
    }

    unsigned short* tb = Ts[w];
    const int r2 = lane >> 2, sg = lane & 3;
    #pragma unroll
    for (int qt = 0; qt < 4; qt++) {
        float r = rsum[qt];
        r += __shfl_xor(r, 16);
        r += __shfl_xor(r, 32);
        float inv = 1.f / r;
        #pragma unroll
        for (int dt = 0; dt < 2; dt++) {
            f32x4 o = Ot[dt][qt];
            uint2 pk;
            pk.x = pk2(o[0] * inv, o[1] * inv);
            pk.y = pk2(o[2] * inv, o[3] * inv);
            *(uint2*)&tb[n * TSTR + dt * 16 + 4 * Q] = pk;
        }
        uint4 v = *(const uint4*)&tb[r2 * TSTR + sg * 8];
        unsigned short* dst = aout +
            ((size_t)h * MW + (size_t)(m * WWIN + qbase + qt * 16 + r2)) * 32 + sg * 8;
        *(uint4*)dst = v;
    }
}

// ---- combine: x1 = x + gathered(out_proj)/count; also write LN2(x1) bf16 ----
__global__ __launch_bounds__(256) void combine_k(
        const float* __restrict__ x, const unsigned short* __restrict__ proj,
        const int* __restrict__ cnt, const int* __restrict__ inv,
        float* __restrict__ x1, unsigned short* __restrict__ x1ln,
        const float* __restrict__ ln2w, const float* __restrict__ ln2b) {
    int lane = threadIdx.x & 63;
    int row = blockIdx.x * 4 + (threadIdx.x >> 6);
    int c = cnt[row];
    if (c > 2) c = 2;
    float4 acc = make_float4(0.f, 0.f, 0.f, 0.f);
    for (int s = 0; s < c; s++) {
        int src = inv[row * 2 + s];
        uint2 p = ((const uint2*)(proj + (size_t)src * C_DIM))[lane];
        acc.x += bf2f(p.x & 0xffffu); acc.y += bf2f(p.x >> 16);
        acc.z += bf2f(p.y & 0xffffu); acc.w += bf2f(p.y >> 16);
    }
    float ic = 1.f / (float)(c > 0 ? c : 1);
    float4 xv = ((const float4*)(x + (size_t)row * C_DIM))[lane];
    float4 r4;
    r4.x = xv.x + acc.x * ic; r4.y = xv.y + acc.y * ic;
    r4.z = xv.z + acc.z * ic; r4.w = xv.w + acc.w * ic;
    ((float4*)(x1 + (size_t)row * C_DIM))[lane] = r4;
    float s = r4.x + r4.y + r4.z + r4.w;
    float q = r4.x * r4.x + r4.y * r4.y + r4.z * r4.z + r4.w * r4.w;
    #pragma unroll
    for (int o = 32; o; o >>= 1) { s += __shfl_xor(s, o); q += __shfl_xor(q, o); }
    float mm = s * (1.f / C_DIM);
    float rv = rsqrtf(q * (1.f / C_DIM) - mm * mm + 1e-5f);
    float4 w4 = ((const float4*)ln2w)[lane];
    float4 b4 = ((const float4*)ln2b)[lane];
    uint2 o2;
    o2.x = pk2((r4.x - mm) * rv * w4.x + b4.x, (r4.y - mm) * rv * w4.y + b4.y);
    o2.y = pk2((r4.z - mm) * rv * w4.z + b4.z, (r4.w - mm) * rv * w4.w + b4.w);
    ((uint2*)(x1ln + (size_t)row * C_DIM))[lane] = o2;
}

__global__ void bnfin_k(const float* __restrict__ hsum, const float* __restrict__ hsq,
        const float* __restrict__ bnw, const float* __restrict__ bnb,
        float* __restrict__ premul, float* __restrict__ preadd, float inv_n) {
    int c = threadIdx.x;
    float m = hsum[c] * inv_n;
    float var = hsq[c] * inv_n - m * m;
    float rstd = rsqrtf(var + 1e-5f);
    float pm = rstd * bnw[c];
    premul[c] = pm;
    preadd[c] = bnb[c] - m * pm;
}

extern "C" void kernel_launch(void* const* d_in, const int* in_sizes, int n_in,
                              void* d_out, int out_size, void* d_ws, size_t ws_size,
                              hipStream_t stream) {
    const float* x    = (const float*)d_in[0];
    const int* widx   = (const int*)d_in[1];
    const float* ln1w = (const float*)d_in[3];
    const float* ln1b = (const float*)d_in[4];
    const float* wqkv = (const float*)d_in[5];
    const float* wproj = (const float*)d_in[6];
    const float* bproj = (const float*)d_in[7];
    const float* ln2w = (const float*)d_in[8];
    const float* ln2b = (const float*)d_in[9];
    const float* w1   = (const float*)d_in[10];
    const float* b1   = (const float*)d_in[11];
    const float* bnw  = (const float*)d_in[12];
    const float* bnb  = (const float*)d_in[13];
    const float* w2   = (const float*)d_in[14];
    const float* b2   = (const float*)d_in[15];
    float* out = (float*)d_out;

    const int N  = in_sizes[0] / C_DIM;   // 25600
    const int MW = in_sizes[1];           // M * 512
    const int M  = MW / WWIN;             // 100

    char* w = (char*)d_ws;
    size_t off = 0;
    auto alloc = [&](size_t bytes) -> void* {
        void* p = w + off;
        off += (bytes + 255) & ~(size_t)255;
        return p;
    };
    // Region A (2048N bytes), time-multiplexed with exact aliasing:
    //   [0,1536N):  qkv planes [24][N][32] bf16   (QKV gemm out, attn in)
    //   [1536N,2048N): x_ln bf16 [N,256]          (ln1 out, QKV gemm A)
    //   [0,1024N):  out_proj bf16 [MW,256]        (proj out, combine in; over dead Q/K planes)
    //   [1024N,1536N): x1ln bf16 [N,256]          (combine out, FFN1 A; over dead V planes)
    //   [0,1024N):  h bf16 [N,512]                (FFN1 out, FFN2 A; over dead out_proj)
    size_t szA = (size_t)MW * C_DIM * 4;  // == 2048N
    char* regA = (char*)alloc(szA);
    unsigned short* qkv = (unsigned short*)regA;
    unsigned short* x_ln = (unsigned short*)(regA + (size_t)1536 * N);
    unsigned short* out_proj = (unsigned short*)regA;
    unsigned short* x1ln = (unsigned short*)(regA + (size_t)1024 * N);
    unsigned short* hbuf = (unsigned short*)regA;
    // Region B (1024N bytes): attn_out bf16 [8][MW][32] -> x1 f32 [N,256]
    size_t szB = (size_t)MW * C_DIM * 2;
    void* regB = alloc(szB);
    unsigned short* attn_out = (unsigned short*)regB;
    float* x1 = (float*)regB;

    unsigned short* wqkv_bf = (unsigned short*)alloc(768 * 256 * 2);
    unsigned short* wproj_bf = (unsigned short*)alloc(256 * 256 * 2);
    unsigned short* w1_bf = (unsigned short*)alloc(512 * 256 * 2);
    unsigned short* w2_bf = (unsigned short*)alloc(256 * 512 * 2);

    int* cnt   = (int*)alloc((size_t)N * 4);
    int* inv   = (int*)alloc((size_t)N * 8);
    int* wlen  = (int*)alloc((size_t)M * 4);
    float* hsum = (float*)alloc(HID_DIM * 4);
    float* hsq  = (float*)alloc(HID_DIM * 4);
    float* premul = (float*)alloc(HID_DIM * 4);
    float* preadd = (float*)alloc(HID_DIM * 4);

    hipMemsetAsync(cnt, 0, (size_t)N * 4, stream);
    hipMemsetAsync(hsum, 0, HID_DIM * 4, stream);
    hipMemsetAsync(hsq, 0, HID_DIM * 4, stream);

    cvtw_k<<<512, 256, 0, stream>>>(wqkv, wproj, w1, w2, wqkv_bf, wproj_bf, w1_bf, w2_bf);
    ln1_k<<<N / 4, 256, 0, stream>>>(x, ln1w, ln1b, x_ln);
    wininv_k<<<M, 512, 0, stream>>>(widx, wlen, cnt, inv);
    // QKV = x_ln @ w_qkv^T, scattered to head planes [24][N][32]
    mgemm_k<256, 0, 5><<<dim3(768 / 128, N / 128), 256, 0, stream>>>(
        x_ln, wqkv_bf, nullptr, qkv, nullptr, nullptr, nullptr, nullptr, nullptr, N, 0);
    attn_mfma_k<<<M * NHEAD * 2, 256, 0, stream>>>(qkv, widx, wlen, attn_out, N, MW);
    // out_proj = attn @ w_proj^T + b_proj (A = head-split planes, AM = MW)
    mgemm_k<256, 4, 7><<<dim3(256 / 128, MW / 128), 256, 0, stream>>>(
        attn_out, wproj_bf, bproj, out_proj, nullptr, nullptr, nullptr,
        nullptr, nullptr, 256, MW);
    combine_k<<<N / 4, 256, 0, stream>>>(x, out_proj, cnt, inv, x1, x1ln, ln2w, ln2b);
    // h = x1ln @ w1^T + b1, bf16 out + fused BN column stats
    mgemm_k<256, 0, 6><<<dim3(512 / 128, N / 128), 256, 0, stream>>>(
        x1ln, w1_bf, b1, hbuf, nullptr, nullptr, nullptr, hsum, hsq, 512, 0);
    bnfin_k<<<1, HID_DIM, 0, stream>>>(hsum, hsq, bnw, bnb, premul, preadd, 1.0f / (float)N);
    // out = x1 + relu(BN(h)) @ w2^T + b2   (A = bf16 h with fused BN+ReLU)
    mgemm_k<512, 2, 4><<<dim3(256 / 128, N / 128), 256, 0, stream>>>(
        hbuf, w2_bf, b2, out, premul, preadd, x1, nullptr, nullptr, 256, 0);
}